// Round 2
// baseline (908.801 us; speedup 1.0000x reference)
//
#include <hip/hip_runtime.h>

#define T_ 2048
#define D_ 4096
#define H_ 32
#define G_ 8
#define HD_ 128

typedef float f32x4 __attribute__((ext_vector_type(4)));
typedef __bf16 bf16x8 __attribute__((ext_vector_type(8)));
typedef unsigned short u16x8 __attribute__((ext_vector_type(8)));

__device__ __forceinline__ unsigned short f2bf(float f) {
  unsigned u = __builtin_bit_cast(unsigned, f);
  u += 0x7FFFu + ((u >> 16) & 1u);
  return (unsigned short)(u >> 16);
}
__device__ __forceinline__ float bf2f(unsigned short h) {
  return __builtin_bit_cast(float, (unsigned)h << 16);
}

__device__ __forceinline__ void gload_lds16(const unsigned short* g, unsigned short* l) {
  __builtin_amdgcn_global_load_lds((const __attribute__((address_space(1))) void*)g,
                                   (__attribute__((address_space(3))) void*)l, 16, 0, 0);
}

// ---------------- elementwise f32 -> bf16 ----------------
__global__ __launch_bounds__(256) void convert_bf16(const float* __restrict__ in,
                                                    unsigned short* __restrict__ out) {
  const size_t i = ((size_t)blockIdx.x * 256 + threadIdx.x) * 8;
  float4 a = *(const float4*)(in + i);
  float4 b = *(const float4*)(in + i + 4);
  u16x8 o;
  o[0] = f2bf(a.x); o[1] = f2bf(a.y); o[2] = f2bf(a.z); o[3] = f2bf(a.w);
  o[4] = f2bf(b.x); o[5] = f2bf(b.y); o[6] = f2bf(b.z); o[7] = f2bf(b.w);
  *(u16x8*)(out + i) = o;
}

// ---------------- tiled transpose + convert: W (R,C) f32 -> Wt (C,R) bf16 ----------------
__global__ __launch_bounds__(256) void transpose_convert(const float* __restrict__ Wm,
                                                         unsigned short* __restrict__ Wt,
                                                         int R, int C) {
  __shared__ float tile[64][65];
  const int r0 = blockIdx.x * 64, c0 = blockIdx.y * 64;
  const int lr4 = threadIdx.x >> 6, lc = threadIdx.x & 63;
#pragma unroll
  for (int i = 0; i < 16; ++i) {
    int r = i * 4 + lr4;
    tile[r][lc] = Wm[(size_t)(r0 + r) * C + c0 + lc];
  }
  __syncthreads();
#pragma unroll
  for (int i = 0; i < 16; ++i) {
    int r = i * 4 + lr4;
    Wt[(size_t)(c0 + r) * R + r0 + lc] = f2bf(tile[lc][r]);
  }
}

// ---------------- transpose v: (T, G*HD) bf16 -> (G, HD, T) bf16 ----------------
__global__ __launch_bounds__(256) void transpose_v(const unsigned short* __restrict__ v,
                                                   unsigned short* __restrict__ vt) {
  __shared__ unsigned short tile[64][65];
  const int t0 = blockIdx.x * 64, d0 = blockIdx.y * 64, g = blockIdx.z;
  const int lr4 = threadIdx.x >> 6, lc = threadIdx.x & 63;
#pragma unroll
  for (int i = 0; i < 16; ++i) {
    int r = i * 4 + lr4;
    tile[r][lc] = v[(size_t)(t0 + r) * (G_ * HD_) + g * HD_ + d0 + lc];
  }
  __syncthreads();
#pragma unroll
  for (int i = 0; i < 16; ++i) {
    int r = i * 4 + lr4;
    vt[((size_t)g * HD_ + d0 + r) * T_ + t0 + lc] = tile[lc][r];
  }
}

// ---------------- RMSNorm + RoPE; (T, NH*HD) bf16 -> (NH, T, HD) bf16 ----------------
__global__ __launch_bounds__(256) void norm_rope(const unsigned short* __restrict__ raw,
                                                 unsigned short* __restrict__ outp,
                                                 const float* __restrict__ w,
                                                 const float* __restrict__ cs,
                                                 const float* __restrict__ sn, int NH) {
  const int row = blockIdx.x * 4 + (threadIdx.x >> 6);
  const int lane = threadIdx.x & 63;
  const int t = row / NH, h = row - t * NH;
  const unsigned short* src = raw + (size_t)row * HD_;
  float u1 = bf2f(src[lane]);
  float u2 = bf2f(src[lane + 64]);
  float ss = u1 * u1 + u2 * u2;
#pragma unroll
  for (int m = 1; m < 64; m <<= 1) ss += __shfl_xor(ss, m);
  float rr = rsqrtf(ss * (1.f / 128.f) + 1e-6f);
  float c = cs[(size_t)t * HD_ + lane];  // cos[d] == cos[d+64] (concat(freqs,freqs))
  float s = sn[(size_t)t * HD_ + lane];
  float a = u1 * rr * w[lane];
  float b = u2 * rr * w[lane + 64];
  unsigned short* dst = outp + ((size_t)h * T_ + t) * HD_;
  dst[lane]      = f2bf(a * c - b * s);
  dst[lane + 64] = f2bf(b * c + a * s);
}

// ---------------- m97-style GEMM: C(M,N) = A(M,K)bf16 * Bt(N,K)bf16 ----------------
template <int OUTF32>
__global__ __launch_bounds__(256) void gemm_bt(const unsigned short* __restrict__ A,
                                               const unsigned short* __restrict__ Bt,
                                               void* __restrict__ Cv, int M, int N, int K) {
  __shared__ __align__(16) unsigned short As[128 * 32];
  __shared__ __align__(16) unsigned short Bs[128 * 32];
  const int tid = threadIdx.x;
  const int wid = tid >> 6, lane = tid & 63;
  const int lr = lane & 15, lhi = lane >> 4;
  const int brow = blockIdx.x * 128, bcol = blockIdx.y * 128;
  const int wr = wid >> 1, wc = wid & 1;
  f32x4 acc[4][4];
#pragma unroll
  for (int m = 0; m < 4; ++m)
#pragma unroll
    for (int n = 0; n < 4; ++n) acc[m][n] = (f32x4){0.f, 0.f, 0.f, 0.f};

  const int srow = wid * 16 + (lane >> 2);
  const int scol = (lane & 3) * 8;
  const unsigned short* ga = A + (size_t)(brow + srow) * K + scol;
  const unsigned short* gb = Bt + (size_t)(bcol + srow) * K + scol;
  unsigned short* la = &As[wid * 512];
  unsigned short* lb = &Bs[wid * 512];

  for (int kt = 0; kt < K; kt += 32) {
    gload_lds16(ga + kt, la);
    gload_lds16(ga + (size_t)64 * K + kt, la + 2048);
    gload_lds16(gb + kt, lb);
    gload_lds16(gb + (size_t)64 * K + kt, lb + 2048);
    __syncthreads();
    bf16x8 af[4], bv[4];
#pragma unroll
    for (int m = 0; m < 4; ++m) af[m] = *(const bf16x8*)&As[(wr * 64 + m * 16 + lr) * 32 + lhi * 8];
#pragma unroll
    for (int n = 0; n < 4; ++n) bv[n] = *(const bf16x8*)&Bs[(wc * 64 + n * 16 + lr) * 32 + lhi * 8];
#pragma unroll
    for (int m = 0; m < 4; ++m)
#pragma unroll
      for (int n = 0; n < 4; ++n)
        acc[m][n] = __builtin_amdgcn_mfma_f32_16x16x32_bf16(af[m], bv[n], acc[m][n], 0, 0, 0);
    __syncthreads();
  }
#pragma unroll
  for (int m = 0; m < 4; ++m)
#pragma unroll
    for (int n = 0; n < 4; ++n) {
      int col = bcol + wc * 64 + n * 16 + lr;
#pragma unroll
      for (int r = 0; r < 4; ++r) {
        int row = brow + wr * 64 + m * 16 + lhi * 4 + r;
        if (OUTF32)
          ((float*)Cv)[(size_t)row * N + col] = acc[m][n][r];
        else
          ((unsigned short*)Cv)[(size_t)row * N + col] = f2bf(acc[m][n][r]);
      }
    }
}

// ---------------- causal flash attention ----------------
// 4 waves/block, each wave owns an independent 16-row q-tile; KVBLK=64.
// No barriers: P round-trips through a PER-WAVE private LDS slice (within-wave
// ds_write -> ds_read dependency, compiler inserts lgkmcnt waits).
__global__ __launch_bounds__(256) void flash_attn(const unsigned short* __restrict__ q,
                                                  const unsigned short* __restrict__ k,
                                                  const unsigned short* __restrict__ vt,
                                                  unsigned short* __restrict__ attnb) {
  const int h = blockIdx.y;
  const int g = h >> 2;  // GS = 4
  const int qc = gridDim.x - 1 - blockIdx.x;  // heavy chunks dispatched first
  const int wid = threadIdx.x >> 6;
  const int lane = threadIdx.x & 63;
  const int lr = lane & 15, lhi = lane >> 4;
  const int q0 = qc * 64 + wid * 16;
  __shared__ __align__(16) unsigned short p_lds_all[4][16 * 64];
  unsigned short* p_lds = p_lds_all[wid];

  // scale * log2(e): softmax computed with exp2
  const float scale2 = 0.08838834764831845f * 1.4426950408889634f;

  bf16x8 qf[4];
  {
    const unsigned short* qrow = q + ((size_t)h * T_ + q0 + lr) * HD_ + lhi * 8;
#pragma unroll
    for (int c = 0; c < 4; ++c) qf[c] = *(const bf16x8*)(qrow + c * 32);
  }
  f32x4 accO[8];
#pragma unroll
  for (int i = 0; i < 8; ++i) accO[i] = (f32x4){0.f, 0.f, 0.f, 0.f};
  float mrow[4] = {-3e38f, -3e38f, -3e38f, -3e38f};
  float lrow[4] = {0.f, 0.f, 0.f, 0.f};

  const int ntile = qc + 1;  // KV tiles of 64
  const unsigned short* kbase = k + ((size_t)g * T_ + lr) * HD_ + lhi * 8;
  const unsigned short* vbase = vt + ((size_t)g * HD_ + lr) * T_ + lhi * 8;

  for (int kt = 0; kt < ntile; ++kt) {
    const int kv0 = kt << 6;
    f32x4 s[4];
#pragma unroll
    for (int j = 0; j < 4; ++j) {
      s[j] = (f32x4){0.f, 0.f, 0.f, 0.f};
      const unsigned short* kr = kbase + (size_t)(kv0 + j * 16) * HD_;
#pragma unroll
      for (int c = 0; c < 4; ++c)
        s[j] = __builtin_amdgcn_mfma_f32_16x16x32_bf16(qf[c], *(const bf16x8*)(kr + c * 32),
                                                       s[j], 0, 0, 0);
    }
    // scale (+ mask on the last tile only; all earlier tiles are fully unmasked)
    if (kt == ntile - 1) {
#pragma unroll
      for (int j = 0; j < 4; ++j)
#pragma unroll
        for (int r = 0; r < 4; ++r)
          s[j][r] = (kv0 + j * 16 + lr <= q0 + lhi * 4 + r) ? s[j][r] * scale2 : -3e38f;
    } else {
#pragma unroll
      for (int j = 0; j < 4; ++j)
#pragma unroll
        for (int r = 0; r < 4; ++r) s[j][r] *= scale2;
    }
    float pm[4], alpha[4], psum[4];
#pragma unroll
    for (int r = 0; r < 4; ++r)
      pm[r] = fmaxf(fmaxf(s[0][r], s[1][r]), fmaxf(s[2][r], s[3][r]));
#pragma unroll
    for (int m = 1; m < 16; m <<= 1)
#pragma unroll
      for (int r = 0; r < 4; ++r) pm[r] = fmaxf(pm[r], __shfl_xor(pm[r], m));
#pragma unroll
    for (int r = 0; r < 4; ++r) {
      float mnew = fmaxf(mrow[r], pm[r]);
      alpha[r] = __builtin_amdgcn_exp2f(mrow[r] - mnew);
      mrow[r] = mnew;
#pragma unroll
      for (int j = 0; j < 4; ++j) s[j][r] = __builtin_amdgcn_exp2f(s[j][r] - mnew);
      psum[r] = (s[0][r] + s[1][r]) + (s[2][r] + s[3][r]);
    }
#pragma unroll
    for (int m = 1; m < 16; m <<= 1)
#pragma unroll
      for (int r = 0; r < 4; ++r) psum[r] += __shfl_xor(psum[r], m);
#pragma unroll
    for (int r = 0; r < 4; ++r) lrow[r] = lrow[r] * alpha[r] + psum[r];
#pragma unroll
    for (int dt = 0; dt < 8; ++dt)
#pragma unroll
      for (int r = 0; r < 4; ++r) accO[dt][r] *= alpha[r];
    // P -> per-wave LDS slice (no barrier needed: same-wave RAW through LDS)
#pragma unroll
    for (int j = 0; j < 4; ++j)
#pragma unroll
      for (int r = 0; r < 4; ++r)
        p_lds[(lhi * 4 + r) * 64 + j * 16 + lr] = f2bf(s[j][r]);
    bf16x8 pa0 = *(const bf16x8*)&p_lds[lr * 64 + lhi * 8];
    bf16x8 pa1 = *(const bf16x8*)&p_lds[lr * 64 + 32 + lhi * 8];
    const unsigned short* vb = vbase + kv0;
#pragma unroll
    for (int dt = 0; dt < 8; ++dt) {
      const unsigned short* vr = vb + (size_t)dt * 16 * T_;
      accO[dt] = __builtin_amdgcn_mfma_f32_16x16x32_bf16(pa0, *(const bf16x8*)vr, accO[dt], 0, 0, 0);
      accO[dt] = __builtin_amdgcn_mfma_f32_16x16x32_bf16(pa1, *(const bf16x8*)(vr + 32), accO[dt], 0, 0, 0);
    }
  }
#pragma unroll
  for (int r = 0; r < 4; ++r) {
    float inv = 1.f / lrow[r];
    size_t rowoff = (size_t)(q0 + lhi * 4 + r) * (H_ * HD_) + h * HD_;
#pragma unroll
    for (int dt = 0; dt < 8; ++dt) attnb[rowoff + dt * 16 + lr] = f2bf(accO[dt][r] * inv);
  }
}

extern "C" void kernel_launch(void* const* d_in, const int* in_sizes, int n_in,
                              void* d_out, int out_size, void* d_ws, size_t ws_size,
                              hipStream_t stream) {
  const float* x = (const float*)d_in[0];
  // d_in[1] = mask (bool) — causal mask computed analytically, unused
  const float* cosT = (const float*)d_in[2];
  const float* sinT = (const float*)d_in[3];
  const float* Wq = (const float*)d_in[4];
  const float* Wk = (const float*)d_in[5];
  const float* Wv = (const float*)d_in[6];
  const float* Wo = (const float*)d_in[7];
  const float* qn = (const float*)d_in[8];
  const float* kn = (const float*)d_in[9];

  unsigned char* w = (unsigned char*)d_ws;
  unsigned short* xb    = (unsigned short*)(w);              // 16 MB (T,D) bf16
  unsigned short* WqT   = (unsigned short*)(w + 16777216);   // 32 MB (4096,4096)
  unsigned short* WkT   = (unsigned short*)(w + 50331648);   // 8 MB (1024,4096)
  unsigned short* WvT   = (unsigned short*)(w + 58720256);   // 8 MB
  unsigned short* qrawb = (unsigned short*)(w + 67108864);   // 16 MB (T, H*HD)
  unsigned short* krawb = (unsigned short*)(w + 83886080);   // 4 MB (T, G*HD)
  unsigned short* vrawb = (unsigned short*)(w + 88080384);   // 4 MB
  unsigned short* qbuf  = (unsigned short*)(w + 92274688);   // 16 MB (H,T,HD)
  unsigned short* kbuf  = (unsigned short*)(w + 109051904);  // 4 MB (G,T,HD)
  unsigned short* vtb   = (unsigned short*)(w + 113246208);  // 4 MB (G,HD,T)  -> total 117.4 MB
  unsigned short* WoT   = WqT;  // alias: Wq tile dead after QKV GEMMs
  unsigned short* attnb = xb;   // alias: x dead after QKV GEMMs

  convert_bf16<<<dim3(4096), dim3(256), 0, stream>>>(x, xb);
  transpose_convert<<<dim3(64, 64), dim3(256), 0, stream>>>(Wq, WqT, 4096, 4096);
  transpose_convert<<<dim3(64, 16), dim3(256), 0, stream>>>(Wk, WkT, 4096, 1024);
  transpose_convert<<<dim3(64, 16), dim3(256), 0, stream>>>(Wv, WvT, 4096, 1024);

  gemm_bt<0><<<dim3(16, 32), dim3(256), 0, stream>>>(xb, WqT, (void*)qrawb, 2048, 4096, 4096);
  gemm_bt<0><<<dim3(16, 8), dim3(256), 0, stream>>>(xb, WkT, (void*)krawb, 2048, 1024, 4096);
  gemm_bt<0><<<dim3(16, 8), dim3(256), 0, stream>>>(xb, WvT, (void*)vrawb, 2048, 1024, 4096);

  norm_rope<<<dim3(16384), dim3(256), 0, stream>>>(qrawb, qbuf, qn, cosT, sinT, H_);
  norm_rope<<<dim3(4096), dim3(256), 0, stream>>>(krawb, kbuf, kn, cosT, sinT, G_);
  transpose_v<<<dim3(32, 2, 8), dim3(256), 0, stream>>>(vrawb, vtb);
  transpose_convert<<<dim3(64, 64), dim3(256), 0, stream>>>(Wo, WoT, 4096, 4096);

  flash_attn<<<dim3(32, 32), dim3(256), 0, stream>>>(qbuf, kbuf, vtb, attnb);

  gemm_bt<1><<<dim3(16, 32), dim3(256), 0, stream>>>(attnb, WoT, d_out, 2048, 4096, 4096);
}

// Round 3
// 621.589 us; speedup vs baseline: 1.4621x; 1.4621x over previous
//
#include <hip/hip_runtime.h>

#define T_ 2048
#define D_ 4096
#define H_ 32
#define G_ 8
#define HD_ 128

typedef float f32x4 __attribute__((ext_vector_type(4)));
typedef __bf16 bf16x8 __attribute__((ext_vector_type(8)));
typedef unsigned short u16x8 __attribute__((ext_vector_type(8)));

__device__ __forceinline__ unsigned short f2bf(float f) {
  unsigned u = __builtin_bit_cast(unsigned, f);
  u += 0x7FFFu + ((u >> 16) & 1u);
  return (unsigned short)(u >> 16);
}
__device__ __forceinline__ float bf2f(unsigned short h) {
  return __builtin_bit_cast(float, (unsigned)h << 16);
}

__device__ __forceinline__ void gload_lds16(const unsigned short* g, unsigned short* l) {
  __builtin_amdgcn_global_load_lds((const __attribute__((address_space(1))) void*)g,
                                   (__attribute__((address_space(3))) void*)l, 16, 0, 0);
}

// ---------------- elementwise f32 -> bf16 ----------------
__global__ __launch_bounds__(256) void convert_bf16(const float* __restrict__ in,
                                                    unsigned short* __restrict__ out) {
  const size_t i = ((size_t)blockIdx.x * 256 + threadIdx.x) * 8;
  float4 a = *(const float4*)(in + i);
  float4 b = *(const float4*)(in + i + 4);
  u16x8 o;
  o[0] = f2bf(a.x); o[1] = f2bf(a.y); o[2] = f2bf(a.z); o[3] = f2bf(a.w);
  o[4] = f2bf(b.x); o[5] = f2bf(b.y); o[6] = f2bf(b.z); o[7] = f2bf(b.w);
  *(u16x8*)(out + i) = o;
}

// ---------------- tiled transpose + convert: W (R,C) f32 -> Wt (C,R) bf16 ----------------
__global__ __launch_bounds__(256) void transpose_convert(const float* __restrict__ Wm,
                                                         unsigned short* __restrict__ Wt,
                                                         int R, int C) {
  __shared__ float tile[64][65];
  const int r0 = blockIdx.x * 64, c0 = blockIdx.y * 64;
  const int lr4 = threadIdx.x >> 6, lc = threadIdx.x & 63;
#pragma unroll
  for (int i = 0; i < 16; ++i) {
    int r = i * 4 + lr4;
    tile[r][lc] = Wm[(size_t)(r0 + r) * C + c0 + lc];
  }
  __syncthreads();
#pragma unroll
  for (int i = 0; i < 16; ++i) {
    int r = i * 4 + lr4;
    Wt[(size_t)(c0 + r) * R + r0 + lc] = f2bf(tile[lc][r]);
  }
}

// ---------------- transpose v: (T, G*HD) bf16 -> (G, HD, T) bf16 ----------------
__global__ __launch_bounds__(256) void transpose_v(const unsigned short* __restrict__ v,
                                                   unsigned short* __restrict__ vt) {
  __shared__ unsigned short tile[64][65];
  const int t0 = blockIdx.x * 64, d0 = blockIdx.y * 64, g = blockIdx.z;
  const int lr4 = threadIdx.x >> 6, lc = threadIdx.x & 63;
#pragma unroll
  for (int i = 0; i < 16; ++i) {
    int r = i * 4 + lr4;
    tile[r][lc] = v[(size_t)(t0 + r) * (G_ * HD_) + g * HD_ + d0 + lc];
  }
  __syncthreads();
#pragma unroll
  for (int i = 0; i < 16; ++i) {
    int r = i * 4 + lr4;
    vt[((size_t)g * HD_ + d0 + r) * T_ + t0 + lc] = tile[lc][r];
  }
}

// ---------------- RMSNorm + RoPE; (T, NH*HD) bf16 -> (NH, T, HD) bf16 ----------------
__global__ __launch_bounds__(256) void norm_rope(const unsigned short* __restrict__ raw,
                                                 unsigned short* __restrict__ outp,
                                                 const float* __restrict__ w,
                                                 const float* __restrict__ cs,
                                                 const float* __restrict__ sn, int NH) {
  const int row = blockIdx.x * 4 + (threadIdx.x >> 6);
  const int lane = threadIdx.x & 63;
  const int t = row / NH, h = row - t * NH;
  const unsigned short* src = raw + (size_t)row * HD_;
  float u1 = bf2f(src[lane]);
  float u2 = bf2f(src[lane + 64]);
  float ss = u1 * u1 + u2 * u2;
#pragma unroll
  for (int m = 1; m < 64; m <<= 1) ss += __shfl_xor(ss, m);
  float rr = rsqrtf(ss * (1.f / 128.f) + 1e-6f);
  float c = cs[(size_t)t * HD_ + lane];  // cos[d] == cos[d+64] (concat(freqs,freqs))
  float s = sn[(size_t)t * HD_ + lane];
  float a = u1 * rr * w[lane];
  float b = u2 * rr * w[lane + 64];
  unsigned short* dst = outp + ((size_t)h * T_ + t) * HD_;
  dst[lane]      = f2bf(a * c - b * s);
  dst[lane + 64] = f2bf(b * c + a * s);
}

// ---------------- m97-style GEMM: C(M,N) = A(M,K)bf16 * Bt(N,K)bf16 ----------------
template <int OUTF32>
__global__ __launch_bounds__(256) void gemm_bt(const unsigned short* __restrict__ A,
                                               const unsigned short* __restrict__ Bt,
                                               void* __restrict__ Cv, int M, int N, int K) {
  __shared__ __align__(16) unsigned short As[128 * 32];
  __shared__ __align__(16) unsigned short Bs[128 * 32];
  const int tid = threadIdx.x;
  const int wid = tid >> 6, lane = tid & 63;
  const int lr = lane & 15, lhi = lane >> 4;
  const int brow = blockIdx.x * 128, bcol = blockIdx.y * 128;
  const int wr = wid >> 1, wc = wid & 1;
  f32x4 acc[4][4];
#pragma unroll
  for (int m = 0; m < 4; ++m)
#pragma unroll
    for (int n = 0; n < 4; ++n) acc[m][n] = (f32x4){0.f, 0.f, 0.f, 0.f};

  const int srow = wid * 16 + (lane >> 2);
  const int scol = (lane & 3) * 8;
  const unsigned short* ga = A + (size_t)(brow + srow) * K + scol;
  const unsigned short* gb = Bt + (size_t)(bcol + srow) * K + scol;
  unsigned short* la = &As[wid * 512];
  unsigned short* lb = &Bs[wid * 512];

  for (int kt = 0; kt < K; kt += 32) {
    gload_lds16(ga + kt, la);
    gload_lds16(ga + (size_t)64 * K + kt, la + 2048);
    gload_lds16(gb + kt, lb);
    gload_lds16(gb + (size_t)64 * K + kt, lb + 2048);
    __syncthreads();
    bf16x8 af[4], bv[4];
#pragma unroll
    for (int m = 0; m < 4; ++m) af[m] = *(const bf16x8*)&As[(wr * 64 + m * 16 + lr) * 32 + lhi * 8];
#pragma unroll
    for (int n = 0; n < 4; ++n) bv[n] = *(const bf16x8*)&Bs[(wc * 64 + n * 16 + lr) * 32 + lhi * 8];
#pragma unroll
    for (int m = 0; m < 4; ++m)
#pragma unroll
      for (int n = 0; n < 4; ++n)
        acc[m][n] = __builtin_amdgcn_mfma_f32_16x16x32_bf16(af[m], bv[n], acc[m][n], 0, 0, 0);
    __syncthreads();
  }
#pragma unroll
  for (int m = 0; m < 4; ++m)
#pragma unroll
    for (int n = 0; n < 4; ++n) {
      int col = bcol + wc * 64 + n * 16 + lr;
#pragma unroll
      for (int r = 0; r < 4; ++r) {
        int row = brow + wr * 64 + m * 16 + lhi * 4 + r;
        if (OUTF32)
          ((float*)Cv)[(size_t)row * N + col] = acc[m][n][r];
        else
          ((unsigned short*)Cv)[(size_t)row * N + col] = f2bf(acc[m][n][r]);
      }
    }
}

// ---------------- causal flash attention ----------------
// Block = 4 waves, 64 q-rows (wave = 16 rows). KV tiles of 64 shared across the
// block via LDS, double-buffered, staged with global_load_lds (width 16).
// Rule #21: LDS dest linear, global SOURCE pre-XOR-swizzled (byte ^= (row&7)<<4),
// all LDS reads apply the same XOR. One __syncthreads per tile (vmcnt(0)+barrier
// makes every wave's staged loads visible to all waves).
__global__ __launch_bounds__(256) void flash_attn(const unsigned short* __restrict__ q,
                                                  const unsigned short* __restrict__ k,
                                                  const unsigned short* __restrict__ vt,
                                                  unsigned short* __restrict__ attnb) {
  const int h = blockIdx.y;
  const int g = h >> 2;  // GS = 4
  const int qc = gridDim.x - 1 - blockIdx.x;  // heavy chunks dispatched first
  const int tid = threadIdx.x;
  const int wid = tid >> 6;
  const int lane = tid & 63;
  const int lr = lane & 15, lhi = lane >> 4;
  const int q0 = qc * 64 + wid * 16;

  __shared__ __align__(16) unsigned short Ks[2][64 * HD_];   // 2 x 16 KB
  __shared__ __align__(16) unsigned short Vs[2][HD_ * 64];   // 2 x 16 KB
  __shared__ __align__(16) unsigned short p_lds_all[4][16 * 64];  // 8 KB
  unsigned short* p_lds = p_lds_all[wid];

  const unsigned short* kg = k + (size_t)g * T_ * HD_;
  const unsigned short* vg = vt + (size_t)g * HD_ * T_;

  // staging source offsets (pre-swizzled): 4 x 16B per thread for each of K, V
  int ko[4], vo[4];
#pragma unroll
  for (int p = 0; p < 4; ++p) {
    int ob = (p * 256 + tid) * 16;
    int krow = ob >> 8, kb = ob & 255;
    ko[p] = krow * HD_ + ((kb ^ ((krow & 7) << 4)) >> 1);
    int vrow = ob >> 7, vb2 = ob & 127;
    vo[p] = vrow * T_ + ((vb2 ^ ((vrow & 7) << 4)) >> 1);
  }
  const int lbase = wid * 64 * 8;  // ushort offset of this wave's first staged slot

  const int sx = (lr & 7) << 4;  // read-side byte XOR (row == lr mod 8 patterns)
  const float scale2 = 0.08838834764831845f * 1.4426950408889634f;  // /sqrt(128)*log2e

  bf16x8 qf[4];
  {
    const unsigned short* qrow = q + ((size_t)h * T_ + q0 + lr) * HD_ + lhi * 8;
#pragma unroll
    for (int c = 0; c < 4; ++c) qf[c] = *(const bf16x8*)(qrow + c * 32);
  }
  f32x4 accO[8];
#pragma unroll
  for (int i = 0; i < 8; ++i) accO[i] = (f32x4){0.f, 0.f, 0.f, 0.f};
  float mrow[4] = {-3e38f, -3e38f, -3e38f, -3e38f};
  float lrow[4] = {0.f, 0.f, 0.f, 0.f};

  const int ntile = qc + 1;

  // prologue: stage tile 0 into buffer 0
#pragma unroll
  for (int p = 0; p < 4; ++p) {
    gload_lds16(kg + ko[p], &Ks[0][p * 2048 + lbase]);
    gload_lds16(vg + vo[p], &Vs[0][p * 2048 + lbase]);
  }
  __syncthreads();

  for (int kt = 0; kt < ntile; ++kt) {
    const int b = kt & 1;
    const int kv0 = kt << 6;
    if (kt + 1 < ntile) {
      const size_t kofs = (size_t)(kv0 + 64) * HD_;
#pragma unroll
      for (int p = 0; p < 4; ++p) {
        gload_lds16(kg + kofs + ko[p], &Ks[b ^ 1][p * 2048 + lbase]);
        gload_lds16(vg + (kv0 + 64) + vo[p], &Vs[b ^ 1][p * 2048 + lbase]);
      }
    }
    // ---- QK^T from LDS (swizzled reads) ----
    f32x4 s[4];
#pragma unroll
    for (int j = 0; j < 4; ++j) {
      s[j] = (f32x4){0.f, 0.f, 0.f, 0.f};
      const int krow = j * 16 + lr;
#pragma unroll
      for (int c = 0; c < 4; ++c) {
        bf16x8 kf = *(const bf16x8*)&Ks[b][krow * HD_ + (((c * 64 + lhi * 16) ^ sx) >> 1)];
        s[j] = __builtin_amdgcn_mfma_f32_16x16x32_bf16(qf[c], kf, s[j], 0, 0, 0);
      }
    }
    // scale (+ mask on the diagonal tile only)
    if (kt == ntile - 1) {
#pragma unroll
      for (int j = 0; j < 4; ++j)
#pragma unroll
        for (int r = 0; r < 4; ++r)
          s[j][r] = (kv0 + j * 16 + lr <= q0 + lhi * 4 + r) ? s[j][r] * scale2 : -3e38f;
    } else {
#pragma unroll
      for (int j = 0; j < 4; ++j)
#pragma unroll
        for (int r = 0; r < 4; ++r) s[j][r] *= scale2;
    }
    // ---- online softmax (16-lane-group shfl reduce) ----
    float pm[4], alpha[4], psum[4];
#pragma unroll
    for (int r = 0; r < 4; ++r)
      pm[r] = fmaxf(fmaxf(s[0][r], s[1][r]), fmaxf(s[2][r], s[3][r]));
#pragma unroll
    for (int m = 1; m < 16; m <<= 1)
#pragma unroll
      for (int r = 0; r < 4; ++r) pm[r] = fmaxf(pm[r], __shfl_xor(pm[r], m));
#pragma unroll
    for (int r = 0; r < 4; ++r) {
      float mnew = fmaxf(mrow[r], pm[r]);
      alpha[r] = __builtin_amdgcn_exp2f(mrow[r] - mnew);
      mrow[r] = mnew;
#pragma unroll
      for (int j = 0; j < 4; ++j) s[j][r] = __builtin_amdgcn_exp2f(s[j][r] - mnew);
      psum[r] = (s[0][r] + s[1][r]) + (s[2][r] + s[3][r]);
    }
#pragma unroll
    for (int m = 1; m < 16; m <<= 1)
#pragma unroll
      for (int r = 0; r < 4; ++r) psum[r] += __shfl_xor(psum[r], m);
#pragma unroll
    for (int r = 0; r < 4; ++r) lrow[r] = lrow[r] * alpha[r] + psum[r];
#pragma unroll
    for (int dt = 0; dt < 8; ++dt)
#pragma unroll
      for (int r = 0; r < 4; ++r) accO[dt][r] *= alpha[r];
    // ---- P -> per-wave LDS slice (swizzled; same-wave RAW, no barrier) ----
#pragma unroll
    for (int j = 0; j < 4; ++j)
#pragma unroll
      for (int r = 0; r < 4; ++r) {
        int prow = lhi * 4 + r;
        p_lds[prow * 64 + ((((j * 16 + lr) * 2) ^ ((prow & 7) << 4)) >> 1)] = f2bf(s[j][r]);
      }
    bf16x8 pa0 = *(const bf16x8*)&p_lds[lr * 64 + (((lhi * 16) ^ sx) >> 1)];
    bf16x8 pa1 = *(const bf16x8*)&p_lds[lr * 64 + (((64 + lhi * 16) ^ sx) >> 1)];
    // ---- PV from LDS V tile (swizzled reads) ----
#pragma unroll
    for (int dt = 0; dt < 8; ++dt) {
      const int vrow = dt * 16 + lr;
      bf16x8 vf0 = *(const bf16x8*)&Vs[b][vrow * 64 + (((lhi * 16) ^ sx) >> 1)];
      bf16x8 vf1 = *(const bf16x8*)&Vs[b][vrow * 64 + (((64 + lhi * 16) ^ sx) >> 1)];
      accO[dt] = __builtin_amdgcn_mfma_f32_16x16x32_bf16(pa0, vf0, accO[dt], 0, 0, 0);
      accO[dt] = __builtin_amdgcn_mfma_f32_16x16x32_bf16(pa1, vf1, accO[dt], 0, 0, 0);
    }
    __syncthreads();  // drain my stage loads (vmcnt 0) + all waves done with buf b
  }
#pragma unroll
  for (int r = 0; r < 4; ++r) {
    float inv = 1.f / lrow[r];
    size_t rowoff = (size_t)(q0 + lhi * 4 + r) * (H_ * HD_) + h * HD_;
#pragma unroll
    for (int dt = 0; dt < 8; ++dt) attnb[rowoff + dt * 16 + lr] = f2bf(accO[dt][r] * inv);
  }
}

extern "C" void kernel_launch(void* const* d_in, const int* in_sizes, int n_in,
                              void* d_out, int out_size, void* d_ws, size_t ws_size,
                              hipStream_t stream) {
  const float* x = (const float*)d_in[0];
  // d_in[1] = mask (bool) — causal mask computed analytically, unused
  const float* cosT = (const float*)d_in[2];
  const float* sinT = (const float*)d_in[3];
  const float* Wq = (const float*)d_in[4];
  const float* Wk = (const float*)d_in[5];
  const float* Wv = (const float*)d_in[6];
  const float* Wo = (const float*)d_in[7];
  const float* qn = (const float*)d_in[8];
  const float* kn = (const float*)d_in[9];

  unsigned char* w = (unsigned char*)d_ws;
  unsigned short* xb    = (unsigned short*)(w);              // 16 MB (T,D) bf16
  unsigned short* WqT   = (unsigned short*)(w + 16777216);   // 32 MB (4096,4096)
  unsigned short* WkT   = (unsigned short*)(w + 50331648);   // 8 MB (1024,4096)
  unsigned short* WvT   = (unsigned short*)(w + 58720256);   // 8 MB
  unsigned short* qrawb = (unsigned short*)(w + 67108864);   // 16 MB (T, H*HD)
  unsigned short* krawb = (unsigned short*)(w + 83886080);   // 4 MB (T, G*HD)
  unsigned short* vrawb = (unsigned short*)(w + 88080384);   // 4 MB
  unsigned short* qbuf  = (unsigned short*)(w + 92274688);   // 16 MB (H,T,HD)
  unsigned short* kbuf  = (unsigned short*)(w + 109051904);  // 4 MB (G,T,HD)
  unsigned short* vtb   = (unsigned short*)(w + 113246208);  // 4 MB (G,HD,T)  -> total 117.4 MB
  unsigned short* WoT   = WqT;  // alias: Wq tile dead after QKV GEMMs
  unsigned short* attnb = xb;   // alias: x dead after QKV GEMMs

  convert_bf16<<<dim3(4096), dim3(256), 0, stream>>>(x, xb);
  transpose_convert<<<dim3(64, 64), dim3(256), 0, stream>>>(Wq, WqT, 4096, 4096);
  transpose_convert<<<dim3(64, 16), dim3(256), 0, stream>>>(Wk, WkT, 4096, 1024);
  transpose_convert<<<dim3(64, 16), dim3(256), 0, stream>>>(Wv, WvT, 4096, 1024);

  gemm_bt<0><<<dim3(16, 32), dim3(256), 0, stream>>>(xb, WqT, (void*)qrawb, 2048, 4096, 4096);
  gemm_bt<0><<<dim3(16, 8), dim3(256), 0, stream>>>(xb, WkT, (void*)krawb, 2048, 1024, 4096);
  gemm_bt<0><<<dim3(16, 8), dim3(256), 0, stream>>>(xb, WvT, (void*)vrawb, 2048, 1024, 4096);

  norm_rope<<<dim3(16384), dim3(256), 0, stream>>>(qrawb, qbuf, qn, cosT, sinT, H_);
  norm_rope<<<dim3(4096), dim3(256), 0, stream>>>(krawb, kbuf, kn, cosT, sinT, G_);
  transpose_v<<<dim3(32, 2, 8), dim3(256), 0, stream>>>(vrawb, vtb);
  transpose_convert<<<dim3(64, 64), dim3(256), 0, stream>>>(Wo, WoT, 4096, 4096);

  flash_attn<<<dim3(32, 32), dim3(256), 0, stream>>>(qbuf, kbuf, vtb, attnb);

  gemm_bt<1><<<dim3(16, 32), dim3(256), 0, stream>>>(attnb, WoT, d_out, 2048, 4096, 4096);
}

// Round 4
// 581.203 us; speedup vs baseline: 1.5637x; 1.0695x over previous
//
#include <hip/hip_runtime.h>

#define T_ 2048
#define D_ 4096
#define H_ 32
#define G_ 8
#define HD_ 128

typedef float f32x4 __attribute__((ext_vector_type(4)));
typedef __bf16 bf16x8 __attribute__((ext_vector_type(8)));
typedef unsigned short u16x8 __attribute__((ext_vector_type(8)));
typedef unsigned short u16x4 __attribute__((ext_vector_type(4)));

__device__ __forceinline__ unsigned short f2bf(float f) {
  unsigned u = __builtin_bit_cast(unsigned, f);
  u += 0x7FFFu + ((u >> 16) & 1u);
  return (unsigned short)(u >> 16);
}
__device__ __forceinline__ float bf2f(unsigned short h) {
  return __builtin_bit_cast(float, (unsigned)h << 16);
}

__device__ __forceinline__ void gload_lds16(const unsigned short* g, unsigned short* l) {
  __builtin_amdgcn_global_load_lds((const __attribute__((address_space(1))) void*)g,
                                   (__attribute__((address_space(3))) void*)l, 16, 0, 0);
}

// ---------------- elementwise f32 -> bf16 ----------------
__global__ __launch_bounds__(256) void convert_bf16(const float* __restrict__ in,
                                                    unsigned short* __restrict__ out) {
  const size_t i = ((size_t)blockIdx.x * 256 + threadIdx.x) * 8;
  float4 a = *(const float4*)(in + i);
  float4 b = *(const float4*)(in + i + 4);
  u16x8 o;
  o[0] = f2bf(a.x); o[1] = f2bf(a.y); o[2] = f2bf(a.z); o[3] = f2bf(a.w);
  o[4] = f2bf(b.x); o[5] = f2bf(b.y); o[6] = f2bf(b.z); o[7] = f2bf(b.w);
  *(u16x8*)(out + i) = o;
}

// ---------------- tiled transpose + convert: W (R,C) f32 -> Wt (C,R) bf16 ----------------
__global__ __launch_bounds__(256) void transpose_convert(const float* __restrict__ Wm,
                                                         unsigned short* __restrict__ Wt,
                                                         int R, int C) {
  __shared__ float tile[64][65];
  const int r0 = blockIdx.x * 64, c0 = blockIdx.y * 64;
  const int lr4 = threadIdx.x >> 6, lc = threadIdx.x & 63;
#pragma unroll
  for (int i = 0; i < 16; ++i) {
    int r = i * 4 + lr4;
    tile[r][lc] = Wm[(size_t)(r0 + r) * C + c0 + lc];
  }
  __syncthreads();
#pragma unroll
  for (int i = 0; i < 16; ++i) {
    int r = i * 4 + lr4;
    Wt[(size_t)(c0 + r) * R + r0 + lc] = f2bf(tile[lc][r]);
  }
}

// ---------------- transpose v: (T, G*HD) bf16 -> (G, HD, T) bf16 ----------------
__global__ __launch_bounds__(256) void transpose_v(const unsigned short* __restrict__ v,
                                                   unsigned short* __restrict__ vt) {
  __shared__ unsigned short tile[64][65];
  const int t0 = blockIdx.x * 64, d0 = blockIdx.y * 64, g = blockIdx.z;
  const int lr4 = threadIdx.x >> 6, lc = threadIdx.x & 63;
#pragma unroll
  for (int i = 0; i < 16; ++i) {
    int r = i * 4 + lr4;
    tile[r][lc] = v[(size_t)(t0 + r) * (G_ * HD_) + g * HD_ + d0 + lc];
  }
  __syncthreads();
#pragma unroll
  for (int i = 0; i < 16; ++i) {
    int r = i * 4 + lr4;
    vt[((size_t)g * HD_ + d0 + r) * T_ + t0 + lc] = tile[lc][r];
  }
}

// ---------------- RMSNorm + RoPE; (T, NH*HD) bf16 -> (NH, T, HD) bf16 ----------------
__global__ __launch_bounds__(256) void norm_rope(const unsigned short* __restrict__ raw,
                                                 unsigned short* __restrict__ outp,
                                                 const float* __restrict__ w,
                                                 const float* __restrict__ cs,
                                                 const float* __restrict__ sn, int NH) {
  const int row = blockIdx.x * 4 + (threadIdx.x >> 6);
  const int lane = threadIdx.x & 63;
  const int t = row / NH, h = row - t * NH;
  const unsigned short* src = raw + (size_t)row * HD_;
  float u1 = bf2f(src[lane]);
  float u2 = bf2f(src[lane + 64]);
  float ss = u1 * u1 + u2 * u2;
#pragma unroll
  for (int m = 1; m < 64; m <<= 1) ss += __shfl_xor(ss, m);
  float rr = rsqrtf(ss * (1.f / 128.f) + 1e-6f);
  float c = cs[(size_t)t * HD_ + lane];  // cos[d] == cos[d+64] (concat(freqs,freqs))
  float s = sn[(size_t)t * HD_ + lane];
  float a = u1 * rr * w[lane];
  float b = u2 * rr * w[lane + 64];
  unsigned short* dst = outp + ((size_t)h * T_ + t) * HD_;
  dst[lane]      = f2bf(a * c - b * s);
  dst[lane + 64] = f2bf(b * c + a * s);
}

// ---------------- m97-style GEMM: C(M,N) = A(M,K)bf16 * Bt(N,K)bf16 ----------------
template <int OUTF32>
__global__ __launch_bounds__(256) void gemm_bt(const unsigned short* __restrict__ A,
                                               const unsigned short* __restrict__ Bt,
                                               void* __restrict__ Cv, int M, int N, int K) {
  __shared__ __align__(16) unsigned short As[128 * 32];
  __shared__ __align__(16) unsigned short Bs[128 * 32];
  const int tid = threadIdx.x;
  const int wid = tid >> 6, lane = tid & 63;
  const int lr = lane & 15, lhi = lane >> 4;
  const int brow = blockIdx.x * 128, bcol = blockIdx.y * 128;
  const int wr = wid >> 1, wc = wid & 1;
  f32x4 acc[4][4];
#pragma unroll
  for (int m = 0; m < 4; ++m)
#pragma unroll
    for (int n = 0; n < 4; ++n) acc[m][n] = (f32x4){0.f, 0.f, 0.f, 0.f};

  const int srow = wid * 16 + (lane >> 2);
  const int scol = (lane & 3) * 8;
  const unsigned short* ga = A + (size_t)(brow + srow) * K + scol;
  const unsigned short* gb = Bt + (size_t)(bcol + srow) * K + scol;
  unsigned short* la = &As[wid * 512];
  unsigned short* lb = &Bs[wid * 512];

  for (int kt = 0; kt < K; kt += 32) {
    gload_lds16(ga + kt, la);
    gload_lds16(ga + (size_t)64 * K + kt, la + 2048);
    gload_lds16(gb + kt, lb);
    gload_lds16(gb + (size_t)64 * K + kt, lb + 2048);
    __syncthreads();
    bf16x8 af[4], bv[4];
#pragma unroll
    for (int m = 0; m < 4; ++m) af[m] = *(const bf16x8*)&As[(wr * 64 + m * 16 + lr) * 32 + lhi * 8];
#pragma unroll
    for (int n = 0; n < 4; ++n) bv[n] = *(const bf16x8*)&Bs[(wc * 64 + n * 16 + lr) * 32 + lhi * 8];
#pragma unroll
    for (int m = 0; m < 4; ++m)
#pragma unroll
      for (int n = 0; n < 4; ++n)
        acc[m][n] = __builtin_amdgcn_mfma_f32_16x16x32_bf16(af[m], bv[n], acc[m][n], 0, 0, 0);
    __syncthreads();
  }
#pragma unroll
  for (int m = 0; m < 4; ++m)
#pragma unroll
    for (int n = 0; n < 4; ++n) {
      int col = bcol + wc * 64 + n * 16 + lr;
#pragma unroll
      for (int r = 0; r < 4; ++r) {
        int row = brow + wr * 64 + m * 16 + lhi * 4 + r;
        if (OUTF32)
          ((float*)Cv)[(size_t)row * N + col] = acc[m][n][r];
        else
          ((unsigned short*)Cv)[(size_t)row * N + col] = f2bf(acc[m][n][r]);
      }
    }
}

// ---------------- causal flash attention ----------------
// 4 waves/block, wave = 16 q-rows, KV tiles of 64 in double-buffered LDS
// (global_load_lds, pre-swizzled source, XOR-swizzled reads).
// SWAPPED QK^T: st = mfma(K, Q) -> lane owns ONE q-row (q = lane&15), its 64
// k-scores live in-register across the 4-lane group (lhi) -> row reduce =
// in-lane + 2 shfl_xor. Scalar running max/sum per lane. T13 defer-max skips
// the O-rescale when max growth <= 8 (log2 domain). T5 setprio around MFMAs.
__global__ __launch_bounds__(256) void flash_attn(const unsigned short* __restrict__ q,
                                                  const unsigned short* __restrict__ k,
                                                  const unsigned short* __restrict__ vt,
                                                  unsigned short* __restrict__ attnb) {
  const int h = blockIdx.y;
  const int g = h >> 2;  // GS = 4
  const int qc = gridDim.x - 1 - blockIdx.x;  // heavy chunks dispatched first
  const int tid = threadIdx.x;
  const int wid = tid >> 6;
  const int lane = tid & 63;
  const int lr = lane & 15, lhi = lane >> 4;
  const int q0 = qc * 64 + wid * 16;

  __shared__ __align__(16) unsigned short Ks[2][64 * HD_];   // 2 x 16 KB
  __shared__ __align__(16) unsigned short Vs[2][HD_ * 64];   // 2 x 16 KB
  __shared__ __align__(16) unsigned short p_lds_all[4][16 * 64];  // 8 KB
  unsigned short* p_lds = p_lds_all[wid];

  const unsigned short* kg = k + (size_t)g * T_ * HD_;
  const unsigned short* vg = vt + (size_t)g * HD_ * T_;

  // staging source offsets (pre-swizzled): 4 x 16B per thread for each of K, V
  int ko[4], vo[4];
#pragma unroll
  for (int p = 0; p < 4; ++p) {
    int ob = (p * 256 + tid) * 16;
    int krow = ob >> 8, kb = ob & 255;
    ko[p] = krow * HD_ + ((kb ^ ((krow & 7) << 4)) >> 1);
    int vrow = ob >> 7, vb2 = ob & 127;
    vo[p] = vrow * T_ + ((vb2 ^ ((vrow & 7) << 4)) >> 1);
  }
  const int lbase = wid * 64 * 8;  // ushort offset of this wave's first staged slot

  const int sx = (lr & 7) << 4;  // read-side byte XOR (rows read are == lr mod 8)
  const float scale2 = 0.08838834764831845f * 1.4426950408889634f;  // /sqrt(128)*log2e

  bf16x8 qf[4];
  {
    const unsigned short* qrow = q + ((size_t)h * T_ + q0 + lr) * HD_ + lhi * 8;
#pragma unroll
    for (int c = 0; c < 4; ++c) qf[c] = *(const bf16x8*)(qrow + c * 32);
  }
  f32x4 accO[8];
#pragma unroll
  for (int i = 0; i < 8; ++i) accO[i] = (f32x4){0.f, 0.f, 0.f, 0.f};
  float mrow = -3e38f;  // running max (log2 domain), q-row = q0 + lr
  float lrow = 0.f;     // running denom

  const int ntile = qc + 1;

  // prologue: stage tile 0 into buffer 0
#pragma unroll
  for (int p = 0; p < 4; ++p) {
    gload_lds16(kg + ko[p], &Ks[0][p * 2048 + lbase]);
    gload_lds16(vg + vo[p], &Vs[0][p * 2048 + lbase]);
  }
  __syncthreads();

  for (int kt = 0; kt < ntile; ++kt) {
    const int b = kt & 1;
    const int kv0 = kt << 6;
    if (kt + 1 < ntile) {
      const size_t kofs = (size_t)(kv0 + 64) * HD_;
#pragma unroll
      for (int p = 0; p < 4; ++p) {
        gload_lds16(kg + kofs + ko[p], &Ks[b ^ 1][p * 2048 + lbase]);
        gload_lds16(vg + (kv0 + 64) + vo[p], &Vs[b ^ 1][p * 2048 + lbase]);
      }
    }
    // ---- QK^T (swapped operands): st[j] holds S^T; lane's q-row = q0+lr,
    //      k = kv0 + j*16 + lhi*4 + r ----
    f32x4 st[4];
    __builtin_amdgcn_s_setprio(1);
#pragma unroll
    for (int j = 0; j < 4; ++j) {
      st[j] = (f32x4){0.f, 0.f, 0.f, 0.f};
      const int krow = j * 16 + lr;
#pragma unroll
      for (int c = 0; c < 4; ++c) {
        bf16x8 kf = *(const bf16x8*)&Ks[b][krow * HD_ + (((c * 64 + lhi * 16) ^ sx) >> 1)];
        st[j] = __builtin_amdgcn_mfma_f32_16x16x32_bf16(kf, qf[c], st[j], 0, 0, 0);
      }
    }
    __builtin_amdgcn_s_setprio(0);
    // scale (+ mask on the diagonal tile only)
    if (kt == ntile - 1) {
#pragma unroll
      for (int j = 0; j < 4; ++j)
#pragma unroll
        for (int r = 0; r < 4; ++r)
          st[j][r] = (kv0 + j * 16 + lhi * 4 + r <= q0 + lr) ? st[j][r] * scale2 : -3e38f;
    } else {
#pragma unroll
      for (int j = 0; j < 4; ++j)
#pragma unroll
        for (int r = 0; r < 4; ++r) st[j][r] *= scale2;
    }
    // ---- row max: in-lane 16 + 2 shfl_xor across the 4-lane group ----
    float pm = st[0][0];
#pragma unroll
    for (int j = 0; j < 4; ++j)
#pragma unroll
      for (int r = 0; r < 4; ++r) pm = fmaxf(pm, st[j][r]);
    pm = fmaxf(pm, __shfl_xor(pm, 16));
    pm = fmaxf(pm, __shfl_xor(pm, 32));
    // ---- T13 defer-max: rescale only when max grew by > 8 (log2 units) ----
    if (!__all(pm - mrow <= 8.f)) {
      float mnew = fmaxf(mrow, pm);
      float al = __builtin_amdgcn_exp2f(mrow - mnew);
      mrow = mnew;
      lrow *= al;
      float a0 = __shfl(al, lhi * 4 + 0);
      float a1 = __shfl(al, lhi * 4 + 1);
      float a2 = __shfl(al, lhi * 4 + 2);
      float a3 = __shfl(al, lhi * 4 + 3);
#pragma unroll
      for (int dt = 0; dt < 8; ++dt) {
        accO[dt][0] *= a0; accO[dt][1] *= a1; accO[dt][2] *= a2; accO[dt][3] *= a3;
      }
    }
    // ---- exp + row sum ----
    float ps = 0.f;
#pragma unroll
    for (int j = 0; j < 4; ++j)
#pragma unroll
      for (int r = 0; r < 4; ++r) {
        float e = __builtin_amdgcn_exp2f(st[j][r] - mrow);
        st[j][r] = e;
        ps += e;
      }
    ps += __shfl_xor(ps, 16);
    ps += __shfl_xor(ps, 32);
    lrow += ps;
    // ---- P^T regs -> P[q][k] LDS (swizzled, packed b64 writes; same-wave RAW) ----
#pragma unroll
    for (int j = 0; j < 4; ++j) {
      u16x4 pw;
      pw[0] = f2bf(st[j][0]); pw[1] = f2bf(st[j][1]);
      pw[2] = f2bf(st[j][2]); pw[3] = f2bf(st[j][3]);
      *(u16x4*)&p_lds[lr * 64 + (((j * 32 + lhi * 8) ^ sx) >> 1)] = pw;
    }
    bf16x8 pa0 = *(const bf16x8*)&p_lds[lr * 64 + (((lhi * 16) ^ sx) >> 1)];
    bf16x8 pa1 = *(const bf16x8*)&p_lds[lr * 64 + (((64 + lhi * 16) ^ sx) >> 1)];
    // ---- PV from LDS V tile (swizzled reads) ----
    __builtin_amdgcn_s_setprio(1);
#pragma unroll
    for (int dt = 0; dt < 8; ++dt) {
      const int vrow = dt * 16 + lr;
      bf16x8 vf0 = *(const bf16x8*)&Vs[b][vrow * 64 + (((lhi * 16) ^ sx) >> 1)];
      bf16x8 vf1 = *(const bf16x8*)&Vs[b][vrow * 64 + (((64 + lhi * 16) ^ sx) >> 1)];
      accO[dt] = __builtin_amdgcn_mfma_f32_16x16x32_bf16(pa0, vf0, accO[dt], 0, 0, 0);
      accO[dt] = __builtin_amdgcn_mfma_f32_16x16x32_bf16(pa1, vf1, accO[dt], 0, 0, 0);
    }
    __builtin_amdgcn_s_setprio(0);
    __syncthreads();  // drain stage loads (vmcnt 0) + all waves done with buf b
  }
  // ---- epilogue: normalize; accO rows are q = lhi*4+r, inv lives in lane q ----
  float rinv = 1.f / lrow;
  float i0 = __shfl(rinv, lhi * 4 + 0);
  float i1 = __shfl(rinv, lhi * 4 + 1);
  float i2 = __shfl(rinv, lhi * 4 + 2);
  float i3 = __shfl(rinv, lhi * 4 + 3);
  float iv[4] = {i0, i1, i2, i3};
#pragma unroll
  for (int r = 0; r < 4; ++r) {
    size_t rowoff = (size_t)(q0 + lhi * 4 + r) * (H_ * HD_) + h * HD_;
#pragma unroll
    for (int dt = 0; dt < 8; ++dt) attnb[rowoff + dt * 16 + lr] = f2bf(accO[dt][r] * iv[r]);
  }
}

extern "C" void kernel_launch(void* const* d_in, const int* in_sizes, int n_in,
                              void* d_out, int out_size, void* d_ws, size_t ws_size,
                              hipStream_t stream) {
  const float* x = (const float*)d_in[0];
  // d_in[1] = mask (bool) — causal mask computed analytically, unused
  const float* cosT = (const float*)d_in[2];
  const float* sinT = (const float*)d_in[3];
  const float* Wq = (const float*)d_in[4];
  const float* Wk = (const float*)d_in[5];
  const float* Wv = (const float*)d_in[6];
  const float* Wo = (const float*)d_in[7];
  const float* qn = (const float*)d_in[8];
  const float* kn = (const float*)d_in[9];

  unsigned char* w = (unsigned char*)d_ws;
  unsigned short* xb    = (unsigned short*)(w);              // 16 MB (T,D) bf16
  unsigned short* WqT   = (unsigned short*)(w + 16777216);   // 32 MB (4096,4096)
  unsigned short* WkT   = (unsigned short*)(w + 50331648);   // 8 MB (1024,4096)
  unsigned short* WvT   = (unsigned short*)(w + 58720256);   // 8 MB
  unsigned short* qrawb = (unsigned short*)(w + 67108864);   // 16 MB (T, H*HD)
  unsigned short* krawb = (unsigned short*)(w + 83886080);   // 4 MB (T, G*HD)
  unsigned short* vrawb = (unsigned short*)(w + 88080384);   // 4 MB
  unsigned short* qbuf  = (unsigned short*)(w + 92274688);   // 16 MB (H,T,HD)
  unsigned short* kbuf  = (unsigned short*)(w + 109051904);  // 4 MB (G,T,HD)
  unsigned short* vtb   = (unsigned short*)(w + 113246208);  // 4 MB (G,HD,T)  -> total 117.4 MB
  unsigned short* WoT   = WqT;  // alias: Wq tile dead after QKV GEMMs
  unsigned short* attnb = xb;   // alias: x dead after QKV GEMMs

  convert_bf16<<<dim3(4096), dim3(256), 0, stream>>>(x, xb);
  transpose_convert<<<dim3(64, 64), dim3(256), 0, stream>>>(Wq, WqT, 4096, 4096);
  transpose_convert<<<dim3(64, 16), dim3(256), 0, stream>>>(Wk, WkT, 4096, 1024);
  transpose_convert<<<dim3(64, 16), dim3(256), 0, stream>>>(Wv, WvT, 4096, 1024);

  gemm_bt<0><<<dim3(16, 32), dim3(256), 0, stream>>>(xb, WqT, (void*)qrawb, 2048, 4096, 4096);
  gemm_bt<0><<<dim3(16, 8), dim3(256), 0, stream>>>(xb, WkT, (void*)krawb, 2048, 1024, 4096);
  gemm_bt<0><<<dim3(16, 8), dim3(256), 0, stream>>>(xb, WvT, (void*)vrawb, 2048, 1024, 4096);

  norm_rope<<<dim3(16384), dim3(256), 0, stream>>>(qrawb, qbuf, qn, cosT, sinT, H_);
  norm_rope<<<dim3(4096), dim3(256), 0, stream>>>(krawb, kbuf, kn, cosT, sinT, G_);
  transpose_v<<<dim3(32, 2, 8), dim3(256), 0, stream>>>(vrawb, vtb);
  transpose_convert<<<dim3(64, 64), dim3(256), 0, stream>>>(Wo, WoT, 4096, 4096);

  flash_attn<<<dim3(32, 32), dim3(256), 0, stream>>>(qbuf, kbuf, vtb, attnb);

  gemm_bt<1><<<dim3(16, 32), dim3(256), 0, stream>>>(attnb, WoT, d_out, 2048, 4096, 4096);
}

// Round 5
// 431.284 us; speedup vs baseline: 2.1072x; 1.3476x over previous
//
#include <hip/hip_runtime.h>

#define T_ 2048
#define D_ 4096
#define H_ 32
#define G_ 8
#define HD_ 128

typedef float f32x4 __attribute__((ext_vector_type(4)));
typedef __bf16 bf16x8 __attribute__((ext_vector_type(8)));
typedef unsigned short u16x8 __attribute__((ext_vector_type(8)));
typedef unsigned short u16x4 __attribute__((ext_vector_type(4)));

__device__ __forceinline__ unsigned short f2bf(float f) {
  unsigned u = __builtin_bit_cast(unsigned, f);
  u += 0x7FFFu + ((u >> 16) & 1u);
  return (unsigned short)(u >> 16);
}
__device__ __forceinline__ float bf2f(unsigned short h) {
  return __builtin_bit_cast(float, (unsigned)h << 16);
}

__device__ __forceinline__ void gload_lds16(const unsigned short* g, unsigned short* l) {
  __builtin_amdgcn_global_load_lds((const __attribute__((address_space(1))) void*)g,
                                   (__attribute__((address_space(3))) void*)l, 16, 0, 0);
}

// ---------------- elementwise f32 -> bf16 ----------------
__global__ __launch_bounds__(256) void convert_bf16(const float* __restrict__ in,
                                                    unsigned short* __restrict__ out) {
  const size_t i = ((size_t)blockIdx.x * 256 + threadIdx.x) * 8;
  float4 a = *(const float4*)(in + i);
  float4 b = *(const float4*)(in + i + 4);
  u16x8 o;
  o[0] = f2bf(a.x); o[1] = f2bf(a.y); o[2] = f2bf(a.z); o[3] = f2bf(a.w);
  o[4] = f2bf(b.x); o[5] = f2bf(b.y); o[6] = f2bf(b.z); o[7] = f2bf(b.w);
  *(u16x8*)(out + i) = o;
}

// ---------------- tiled transpose + convert: W (R,C) f32 -> Wt (C,R) bf16 ----------------
__global__ __launch_bounds__(256) void transpose_convert(const float* __restrict__ Wm,
                                                         unsigned short* __restrict__ Wt,
                                                         int R, int C) {
  __shared__ float tile[64][65];
  const int r0 = blockIdx.x * 64, c0 = blockIdx.y * 64;
  const int lr4 = threadIdx.x >> 6, lc = threadIdx.x & 63;
#pragma unroll
  for (int i = 0; i < 16; ++i) {
    int r = i * 4 + lr4;
    tile[r][lc] = Wm[(size_t)(r0 + r) * C + c0 + lc];
  }
  __syncthreads();
#pragma unroll
  for (int i = 0; i < 16; ++i) {
    int r = i * 4 + lr4;
    Wt[(size_t)(c0 + r) * R + r0 + lc] = f2bf(tile[lc][r]);
  }
}

// ---------------- transpose v: (T, stride) bf16 cols -> (G, HD, T) bf16 ----------------
__global__ __launch_bounds__(256) void transpose_v(const unsigned short* __restrict__ v,
                                                   unsigned short* __restrict__ vt, int stride) {
  __shared__ unsigned short tile[64][65];
  const int t0 = blockIdx.x * 64, d0 = blockIdx.y * 64, g = blockIdx.z;
  const int lr4 = threadIdx.x >> 6, lc = threadIdx.x & 63;
#pragma unroll
  for (int i = 0; i < 16; ++i) {
    int r = i * 4 + lr4;
    tile[r][lc] = v[(size_t)(t0 + r) * stride + g * HD_ + d0 + lc];
  }
  __syncthreads();
#pragma unroll
  for (int i = 0; i < 16; ++i) {
    int r = i * 4 + lr4;
    vt[((size_t)g * HD_ + d0 + r) * T_ + t0 + lc] = tile[lc][r];
  }
}

// ---------------- RMSNorm + RoPE; (T, stride) bf16 -> (NH, T, HD) bf16 ----------------
__global__ __launch_bounds__(256) void norm_rope(const unsigned short* __restrict__ raw,
                                                 int stride,
                                                 unsigned short* __restrict__ outp,
                                                 const float* __restrict__ w,
                                                 const float* __restrict__ cs,
                                                 const float* __restrict__ sn, int NH) {
  const int row = blockIdx.x * 4 + (threadIdx.x >> 6);
  const int lane = threadIdx.x & 63;
  const int t = row / NH, h = row - t * NH;
  const unsigned short* src = raw + (size_t)t * stride + h * HD_;
  float u1 = bf2f(src[lane]);
  float u2 = bf2f(src[lane + 64]);
  float ss = u1 * u1 + u2 * u2;
#pragma unroll
  for (int m = 1; m < 64; m <<= 1) ss += __shfl_xor(ss, m);
  float rr = rsqrtf(ss * (1.f / 128.f) + 1e-6f);
  float c = cs[(size_t)t * HD_ + lane];  // cos[d] == cos[d+64] (concat(freqs,freqs))
  float s = sn[(size_t)t * HD_ + lane];
  float a = u1 * rr * w[lane];
  float b = u2 * rr * w[lane + 64];
  unsigned short* dst = outp + ((size_t)h * T_ + t) * HD_;
  dst[lane]      = f2bf(a * c - b * s);
  dst[lane + 64] = f2bf(b * c + a * s);
}

// ---------------- 256x256 8-phase GEMM: C(M,N) = A(M,K)bf16 * Bt(N,K)bf16 ----------------
// 512 thr = 8 waves (2 Mw x 4 Nw). BK=64, LDS = 2 dbuf x (A 256x64 + B 256x64) bf16 = 128 KB.
// Wave (wr,wcn): C rows {mq*128 + wr*64 + fm*16}, cols {nq*128 + wcn*32 + fn*16}.
// Per K-step 4 phases = C quadrants (mq,nq): (0,0),(0,1),(1,1),(1,0), 16 MFMA each.
// Staging slot-ring: step t issues A1(t+1),B0(t+1) -> other dbuf (P0,P1) and
// A0(t+2),B1(t+2) -> own dbuf (P2,P3; slots freed at P0/P1). Counted vmcnt(4)
// before the step's last barrier retires exactly step t+1's 8 loads; never 0 in loop.
// Swizzle: LDS linear dest, global source slot^=(row&7), reads apply same XOR (2-way = free).
template <int MQ, int NQ>
__device__ __forceinline__ void mfma_quad(f32x4 (&acc)[2][4][2][2], bf16x8 (&af)[4][2],
                                          bf16x8 (&BF)[2][2]) {
  __builtin_amdgcn_s_setprio(1);
#pragma unroll
  for (int fm = 0; fm < 4; ++fm)
#pragma unroll
    for (int fn = 0; fn < 2; ++fn) {
      f32x4 a = acc[MQ][fm][NQ][fn];
      a = __builtin_amdgcn_mfma_f32_16x16x32_bf16(af[fm][0], BF[fn][0], a, 0, 0, 0);
      a = __builtin_amdgcn_mfma_f32_16x16x32_bf16(af[fm][1], BF[fn][1], a, 0, 0, 0);
      acc[MQ][fm][NQ][fn] = a;
    }
  __builtin_amdgcn_s_setprio(0);
}

template <int OUTF32>
__global__ __launch_bounds__(512, 2) void gemm256(const unsigned short* __restrict__ A,
                                                  const unsigned short* __restrict__ Bt,
                                                  void* __restrict__ Cv, int M, int N, int K) {
  __shared__ __align__(16) unsigned short lds[65536];  // A: [2][2][128][64] then B
  const int tid = threadIdx.x;
  const int wid = tid >> 6, lane = tid & 63;
  const int lr = lane & 15, lhi = lane >> 4, lhi8 = lhi * 8;
  const int wr = wid >> 2, wcn = wid & 3;
  const int wr64 = wr * 64, wcn32 = wcn * 32;

  // XCD-aware swizzle (gridDim.x == 8 assumed; nwg % 8 == 0)
  int flat = blockIdx.y * gridDim.x + blockIdx.x;
  int nwg = gridDim.x * gridDim.y;
  int swz = (flat & 7) * (nwg >> 3) + (flat >> 3);
  const int brow = (swz & 7) * 256;
  const int bcol = (swz >> 3) * 256;

  const int nt = K >> 6;

  f32x4 acc[2][4][2][2];
#pragma unroll
  for (int a = 0; a < 2; ++a)
#pragma unroll
    for (int b = 0; b < 4; ++b)
#pragma unroll
      for (int c = 0; c < 2; ++c)
#pragma unroll
        for (int d = 0; d < 2; ++d) acc[a][b][c][d] = (f32x4){0.f, 0.f, 0.f, 0.f};

  // staging source: lane reads global (row, slot^(row&7)); row = wid*16 + l*8 + (lane>>3)
  const int sl8 = ((lane & 7) ^ (lane >> 3)) * 8;
  const size_t gA0 = (size_t)(brow + wid * 16 + (lane >> 3)) * K + sl8;
  const size_t gB0 = (size_t)(bcol + wid * 16 + (lane >> 3)) * K + sl8;
  const int ldst0 = wid * 1024;  // + half*8192 + l*512 (+ dbuf*16384; B adds 32768)

  auto stageA = [&](int ddB, int half, int ktp) {
#pragma unroll
    for (int l = 0; l < 2; ++l)
      gload_lds16(A + gA0 + (size_t)(half * 128 + l * 8) * K + ktp * 64,
                  &lds[ddB + half * 8192 + ldst0 + l * 512]);
  };
  auto stageB = [&](int ddB, int half, int ktp) {
#pragma unroll
    for (int l = 0; l < 2; ++l)
      gload_lds16(Bt + gB0 + (size_t)(half * 128 + l * 8) * K + ktp * 64,
                  &lds[32768 + ddB + half * 8192 + ldst0 + l * 512]);
  };

  bf16x8 af[4][2], bf0[2][2], bf1[2][2];
  auto readA = [&](int dB, int mqOff) {
#pragma unroll
    for (int fm = 0; fm < 4; ++fm) {
      int row = wr64 + fm * 16 + lr;
      int sw = (row & 7) << 3;
      int base = dB + mqOff + row * 64;
      af[fm][0] = *(const bf16x8*)&lds[base + (lhi8 ^ sw)];
      af[fm][1] = *(const bf16x8*)&lds[base + ((32 + lhi8) ^ sw)];
    }
  };
  auto readB = [&](int dB, int nqOff, bf16x8 (&bf)[2][2]) {
#pragma unroll
    for (int fn = 0; fn < 2; ++fn) {
      int row = wcn32 + fn * 16 + lr;
      int sw = (row & 7) << 3;
      int base = 32768 + dB + nqOff + row * 64;
      bf[fn][0] = *(const bf16x8*)&lds[base + (lhi8 ^ sw)];
      bf[fn][1] = *(const bf16x8*)&lds[base + ((32 + lhi8) ^ sw)];
    }
  };

  // prologue: full step0 -> dbuf0; step1 A0,B1 -> dbuf1 (invariant: 4 in flight)
  stageA(0, 0, 0); stageA(0, 1, 0); stageB(0, 0, 0); stageB(0, 1, 0);
  stageA(16384, 0, 1); stageB(16384, 1, 1);
  asm volatile("s_waitcnt vmcnt(4)" ::: "memory");
  __builtin_amdgcn_s_barrier();

  for (int t = 0; t < nt; ++t) {
    const int dB = (t & 1) ? 16384 : 0;
    const int dN = 16384 - dB;
    // P0: quadrant (0,0); reads A(mq0)+B(nq0); stage (t+1).A1 -> next dbuf
    readA(dB, 0);
    readB(dB, 0, bf0);
    if (t + 1 < nt) stageA(dN, 1, t + 1);
    __builtin_amdgcn_s_barrier();
    mfma_quad<0, 0>(acc, af, bf0);
    __builtin_amdgcn_s_barrier();
    // P1: quadrant (0,1); reads B(nq1); stage (t+1).B0 -> next dbuf
    readB(dB, 8192, bf1);
    if (t + 1 < nt) stageB(dN, 0, t + 1);
    __builtin_amdgcn_s_barrier();
    mfma_quad<0, 1>(acc, af, bf1);
    __builtin_amdgcn_s_barrier();
    // P2: quadrant (1,1); reads A(mq1); stage (t+2).A0 -> own dbuf (slot freed at P0)
    readA(dB, 8192);
    if (t + 2 < nt) stageA(dB, 0, t + 2);
    __builtin_amdgcn_s_barrier();
    mfma_quad<1, 1>(acc, af, bf1);
    __builtin_amdgcn_s_barrier();
    // P3: quadrant (1,0); B(nq0) still in regs; stage (t+2).B1 -> own dbuf (freed at P1)
    if (t + 2 < nt) stageB(dB, 1, t + 2);
    __builtin_amdgcn_s_barrier();
    mfma_quad<1, 0>(acc, af, bf0);
    // counted vmcnt BEFORE the step's last barrier: retire step t+1's 8 loads
    if (t < nt - 2) asm volatile("s_waitcnt vmcnt(4)" ::: "memory");
    else if (t == nt - 2) asm volatile("s_waitcnt vmcnt(0)" ::: "memory");
    __builtin_amdgcn_s_barrier();
  }

  // epilogue
#pragma unroll
  for (int mq = 0; mq < 2; ++mq)
#pragma unroll
    for (int fm = 0; fm < 4; ++fm)
#pragma unroll
      for (int nq = 0; nq < 2; ++nq)
#pragma unroll
        for (int fn = 0; fn < 2; ++fn) {
          int col = bcol + nq * 128 + wcn32 + fn * 16 + lr;
#pragma unroll
          for (int r = 0; r < 4; ++r) {
            int row = brow + mq * 128 + wr64 + fm * 16 + lhi * 4 + r;
            if (OUTF32)
              ((float*)Cv)[(size_t)row * N + col] = acc[mq][fm][nq][fn][r];
            else
              ((unsigned short*)Cv)[(size_t)row * N + col] = f2bf(acc[mq][fm][nq][fn][r]);
          }
        }
}

// ---------------- causal flash attention (unchanged from R4) ----------------
__global__ __launch_bounds__(256) void flash_attn(const unsigned short* __restrict__ q,
                                                  const unsigned short* __restrict__ k,
                                                  const unsigned short* __restrict__ vt,
                                                  unsigned short* __restrict__ attnb) {
  const int h = blockIdx.y;
  const int g = h >> 2;  // GS = 4
  const int qc = gridDim.x - 1 - blockIdx.x;  // heavy chunks dispatched first
  const int tid = threadIdx.x;
  const int wid = tid >> 6;
  const int lane = tid & 63;
  const int lr = lane & 15, lhi = lane >> 4;
  const int q0 = qc * 64 + wid * 16;

  __shared__ __align__(16) unsigned short Ks[2][64 * HD_];
  __shared__ __align__(16) unsigned short Vs[2][HD_ * 64];
  __shared__ __align__(16) unsigned short p_lds_all[4][16 * 64];
  unsigned short* p_lds = p_lds_all[wid];

  const unsigned short* kg = k + (size_t)g * T_ * HD_;
  const unsigned short* vg = vt + (size_t)g * HD_ * T_;

  int ko[4], vo[4];
#pragma unroll
  for (int p = 0; p < 4; ++p) {
    int ob = (p * 256 + tid) * 16;
    int krow = ob >> 8, kb = ob & 255;
    ko[p] = krow * HD_ + ((kb ^ ((krow & 7) << 4)) >> 1);
    int vrow = ob >> 7, vb2 = ob & 127;
    vo[p] = vrow * T_ + ((vb2 ^ ((vrow & 7) << 4)) >> 1);
  }
  const int lbase = wid * 64 * 8;

  const int sx = (lr & 7) << 4;
  const float scale2 = 0.08838834764831845f * 1.4426950408889634f;

  bf16x8 qf[4];
  {
    const unsigned short* qrow = q + ((size_t)h * T_ + q0 + lr) * HD_ + lhi * 8;
#pragma unroll
    for (int c = 0; c < 4; ++c) qf[c] = *(const bf16x8*)(qrow + c * 32);
  }
  f32x4 accO[8];
#pragma unroll
  for (int i = 0; i < 8; ++i) accO[i] = (f32x4){0.f, 0.f, 0.f, 0.f};
  float mrow = -3e38f;
  float lrow = 0.f;

  const int ntile = qc + 1;

#pragma unroll
  for (int p = 0; p < 4; ++p) {
    gload_lds16(kg + ko[p], &Ks[0][p * 2048 + lbase]);
    gload_lds16(vg + vo[p], &Vs[0][p * 2048 + lbase]);
  }
  __syncthreads();

  for (int kt = 0; kt < ntile; ++kt) {
    const int b = kt & 1;
    const int kv0 = kt << 6;
    if (kt + 1 < ntile) {
      const size_t kofs = (size_t)(kv0 + 64) * HD_;
#pragma unroll
      for (int p = 0; p < 4; ++p) {
        gload_lds16(kg + kofs + ko[p], &Ks[b ^ 1][p * 2048 + lbase]);
        gload_lds16(vg + (kv0 + 64) + vo[p], &Vs[b ^ 1][p * 2048 + lbase]);
      }
    }
    f32x4 st[4];
    __builtin_amdgcn_s_setprio(1);
#pragma unroll
    for (int j = 0; j < 4; ++j) {
      st[j] = (f32x4){0.f, 0.f, 0.f, 0.f};
      const int krow = j * 16 + lr;
#pragma unroll
      for (int c = 0; c < 4; ++c) {
        bf16x8 kf = *(const bf16x8*)&Ks[b][krow * HD_ + (((c * 64 + lhi * 16) ^ sx) >> 1)];
        st[j] = __builtin_amdgcn_mfma_f32_16x16x32_bf16(kf, qf[c], st[j], 0, 0, 0);
      }
    }
    __builtin_amdgcn_s_setprio(0);
    if (kt == ntile - 1) {
#pragma unroll
      for (int j = 0; j < 4; ++j)
#pragma unroll
        for (int r = 0; r < 4; ++r)
          st[j][r] = (kv0 + j * 16 + lhi * 4 + r <= q0 + lr) ? st[j][r] * scale2 : -3e38f;
    } else {
#pragma unroll
      for (int j = 0; j < 4; ++j)
#pragma unroll
        for (int r = 0; r < 4; ++r) st[j][r] *= scale2;
    }
    float pm = st[0][0];
#pragma unroll
    for (int j = 0; j < 4; ++j)
#pragma unroll
      for (int r = 0; r < 4; ++r) pm = fmaxf(pm, st[j][r]);
    pm = fmaxf(pm, __shfl_xor(pm, 16));
    pm = fmaxf(pm, __shfl_xor(pm, 32));
    if (!__all(pm - mrow <= 8.f)) {
      float mnew = fmaxf(mrow, pm);
      float al = __builtin_amdgcn_exp2f(mrow - mnew);
      mrow = mnew;
      lrow *= al;
      float a0 = __shfl(al, lhi * 4 + 0);
      float a1 = __shfl(al, lhi * 4 + 1);
      float a2 = __shfl(al, lhi * 4 + 2);
      float a3 = __shfl(al, lhi * 4 + 3);
#pragma unroll
      for (int dt = 0; dt < 8; ++dt) {
        accO[dt][0] *= a0; accO[dt][1] *= a1; accO[dt][2] *= a2; accO[dt][3] *= a3;
      }
    }
    float ps = 0.f;
#pragma unroll
    for (int j = 0; j < 4; ++j)
#pragma unroll
      for (int r = 0; r < 4; ++r) {
        float e = __builtin_amdgcn_exp2f(st[j][r] - mrow);
        st[j][r] = e;
        ps += e;
      }
    ps += __shfl_xor(ps, 16);
    ps += __shfl_xor(ps, 32);
    lrow += ps;
#pragma unroll
    for (int j = 0; j < 4; ++j) {
      u16x4 pw;
      pw[0] = f2bf(st[j][0]); pw[1] = f2bf(st[j][1]);
      pw[2] = f2bf(st[j][2]); pw[3] = f2bf(st[j][3]);
      *(u16x4*)&p_lds[lr * 64 + (((j * 32 + lhi * 8) ^ sx) >> 1)] = pw;
    }
    bf16x8 pa0 = *(const bf16x8*)&p_lds[lr * 64 + (((lhi * 16) ^ sx) >> 1)];
    bf16x8 pa1 = *(const bf16x8*)&p_lds[lr * 64 + (((64 + lhi * 16) ^ sx) >> 1)];
    __builtin_amdgcn_s_setprio(1);
#pragma unroll
    for (int dt = 0; dt < 8; ++dt) {
      const int vrow = dt * 16 + lr;
      bf16x8 vf0 = *(const bf16x8*)&Vs[b][vrow * 64 + (((lhi * 16) ^ sx) >> 1)];
      bf16x8 vf1 = *(const bf16x8*)&Vs[b][vrow * 64 + (((64 + lhi * 16) ^ sx) >> 1)];
      accO[dt] = __builtin_amdgcn_mfma_f32_16x16x32_bf16(pa0, vf0, accO[dt], 0, 0, 0);
      accO[dt] = __builtin_amdgcn_mfma_f32_16x16x32_bf16(pa1, vf1, accO[dt], 0, 0, 0);
    }
    __builtin_amdgcn_s_setprio(0);
    __syncthreads();
  }
  float rinv = 1.f / lrow;
  float i0 = __shfl(rinv, lhi * 4 + 0);
  float i1 = __shfl(rinv, lhi * 4 + 1);
  float i2 = __shfl(rinv, lhi * 4 + 2);
  float i3 = __shfl(rinv, lhi * 4 + 3);
  float iv[4] = {i0, i1, i2, i3};
#pragma unroll
  for (int r = 0; r < 4; ++r) {
    size_t rowoff = (size_t)(q0 + lhi * 4 + r) * (H_ * HD_) + h * HD_;
#pragma unroll
    for (int dt = 0; dt < 8; ++dt) attnb[rowoff + dt * 16 + lr] = f2bf(accO[dt][r] * iv[r]);
  }
}

extern "C" void kernel_launch(void* const* d_in, const int* in_sizes, int n_in,
                              void* d_out, int out_size, void* d_ws, size_t ws_size,
                              hipStream_t stream) {
  const float* x = (const float*)d_in[0];
  // d_in[1] = mask (bool) — causal mask computed analytically, unused
  const float* cosT = (const float*)d_in[2];
  const float* sinT = (const float*)d_in[3];
  const float* Wq = (const float*)d_in[4];
  const float* Wk = (const float*)d_in[5];
  const float* Wv = (const float*)d_in[6];
  const float* Wo = (const float*)d_in[7];
  const float* qn = (const float*)d_in[8];
  const float* kn = (const float*)d_in[9];

  unsigned char* w = (unsigned char*)d_ws;
  unsigned short* xb     = (unsigned short*)(w);             // 16 MB (T,D) bf16
  unsigned short* WqkvT  = (unsigned short*)(w + 16777216);  // 48 MB (6144,4096) bf16
  unsigned short* qkvraw = (unsigned short*)(w + 67108864);  // 24 MB (T,6144) bf16
  unsigned short* qbuf   = (unsigned short*)(w + 92274688);  // 16 MB (H,T,HD)
  unsigned short* kbuf   = (unsigned short*)(w + 109051904); // 4 MB (G,T,HD)
  unsigned short* vtb    = (unsigned short*)(w + 113246208); // 4 MB (G,HD,T) -> 117.4 MB
  unsigned short* WoT    = WqkvT;  // alias: Wqkv dead after QKV GEMM (32 MB fits in 48)
  unsigned short* attnb  = xb;     // alias: x dead after QKV GEMM

  convert_bf16<<<dim3(4096), dim3(256), 0, stream>>>(x, xb);
  transpose_convert<<<dim3(64, 64), dim3(256), 0, stream>>>(Wq, WqkvT, 4096, 4096);
  transpose_convert<<<dim3(64, 16), dim3(256), 0, stream>>>(Wk, WqkvT + (size_t)4096 * 4096, 4096, 1024);
  transpose_convert<<<dim3(64, 16), dim3(256), 0, stream>>>(Wv, WqkvT + (size_t)5120 * 4096, 4096, 1024);

  // fused QKV projection: (2048,4096) x (6144,4096)^T -> (2048,6144) bf16
  gemm256<0><<<dim3(8, 24), dim3(512), 0, stream>>>(xb, WqkvT, (void*)qkvraw, 2048, 6144, 4096);

  norm_rope<<<dim3(16384), dim3(256), 0, stream>>>(qkvraw, 6144, qbuf, qn, cosT, sinT, H_);
  norm_rope<<<dim3(4096), dim3(256), 0, stream>>>(qkvraw + 4096, 6144, kbuf, kn, cosT, sinT, G_);
  transpose_v<<<dim3(32, 2, 8), dim3(256), 0, stream>>>(qkvraw + 5120, vtb, 6144);
  transpose_convert<<<dim3(64, 64), dim3(256), 0, stream>>>(Wo, WoT, 4096, 4096);

  flash_attn<<<dim3(32, 32), dim3(256), 0, stream>>>(qbuf, kbuf, vtb, attnb);

  gemm256<1><<<dim3(8, 16), dim3(512), 0, stream>>>(attnb, WoT, d_out, 2048, 4096, 4096);
}

// Round 6
// 370.680 us; speedup vs baseline: 2.4517x; 1.1635x over previous
//
#include <hip/hip_runtime.h>

#define T_ 2048
#define D_ 4096
#define H_ 32
#define G_ 8
#define HD_ 128

typedef float f32x4 __attribute__((ext_vector_type(4)));
typedef __bf16 bf16x8 __attribute__((ext_vector_type(8)));
typedef unsigned short u16x8 __attribute__((ext_vector_type(8)));
typedef unsigned short u16x4 __attribute__((ext_vector_type(4)));

__device__ __forceinline__ unsigned short f2bf(float f) {
  unsigned u = __builtin_bit_cast(unsigned, f);
  u += 0x7FFFu + ((u >> 16) & 1u);
  return (unsigned short)(u >> 16);
}
__device__ __forceinline__ float bf2f(unsigned short h) {
  return __builtin_bit_cast(float, (unsigned)h << 16);
}

__device__ __forceinline__ void gload_lds16(const unsigned short* g, unsigned short* l) {
  __builtin_amdgcn_global_load_lds((const __attribute__((address_space(1))) void*)g,
                                   (__attribute__((address_space(3))) void*)l, 16, 0, 0);
}

// ---------------- elementwise f32 -> bf16 ----------------
__global__ __launch_bounds__(256) void convert_bf16(const float* __restrict__ in,
                                                    unsigned short* __restrict__ out) {
  const size_t i = ((size_t)blockIdx.x * 256 + threadIdx.x) * 8;
  float4 a = *(const float4*)(in + i);
  float4 b = *(const float4*)(in + i + 4);
  u16x8 o;
  o[0] = f2bf(a.x); o[1] = f2bf(a.y); o[2] = f2bf(a.z); o[3] = f2bf(a.w);
  o[4] = f2bf(b.x); o[5] = f2bf(b.y); o[6] = f2bf(b.z); o[7] = f2bf(b.w);
  *(u16x8*)(out + i) = o;
}

// ---------------- f32 halves add: out = p[0..] + p[half..] ----------------
__global__ __launch_bounds__(256) void add_halves(const float* __restrict__ p,
                                                  float* __restrict__ out) {
  const size_t half = (size_t)2048 * 4096;
  const size_t stride = (size_t)gridDim.x * 256 * 4;
  for (size_t i = ((size_t)blockIdx.x * 256 + threadIdx.x) * 4; i < half; i += stride) {
    float4 a = *(const float4*)(p + i);
    float4 b = *(const float4*)(p + half + i);
    a.x += b.x; a.y += b.y; a.z += b.z; a.w += b.w;
    *(float4*)(out + i) = a;
  }
}

// ---------------- tiled transpose + convert: W (R,C) f32 -> Wt (C,R) bf16 ----------------
__global__ __launch_bounds__(256) void transpose_convert(const float* __restrict__ Wm,
                                                         unsigned short* __restrict__ Wt,
                                                         int R, int C) {
  __shared__ float tile[64][65];
  const int r0 = blockIdx.x * 64, c0 = blockIdx.y * 64;
  const int lr4 = threadIdx.x >> 6, lc = threadIdx.x & 63;
#pragma unroll
  for (int i = 0; i < 16; ++i) {
    int r = i * 4 + lr4;
    tile[r][lc] = Wm[(size_t)(r0 + r) * C + c0 + lc];
  }
  __syncthreads();
#pragma unroll
  for (int i = 0; i < 16; ++i) {
    int r = i * 4 + lr4;
    Wt[(size_t)(c0 + r) * R + r0 + lc] = f2bf(tile[lc][r]);
  }
}

// ---------------- transpose v: (T, stride) bf16 cols -> (G, HD, T) bf16 ----------------
__global__ __launch_bounds__(256) void transpose_v(const unsigned short* __restrict__ v,
                                                   unsigned short* __restrict__ vt, int stride) {
  __shared__ unsigned short tile[64][65];
  const int t0 = blockIdx.x * 64, d0 = blockIdx.y * 64, g = blockIdx.z;
  const int lr4 = threadIdx.x >> 6, lc = threadIdx.x & 63;
#pragma unroll
  for (int i = 0; i < 16; ++i) {
    int r = i * 4 + lr4;
    tile[r][lc] = v[(size_t)(t0 + r) * stride + g * HD_ + d0 + lc];
  }
  __syncthreads();
#pragma unroll
  for (int i = 0; i < 16; ++i) {
    int r = i * 4 + lr4;
    vt[((size_t)g * HD_ + d0 + r) * T_ + t0 + lc] = tile[lc][r];
  }
}

// ---------------- RMSNorm + RoPE; (T, stride) bf16 -> (NH, T, HD) bf16 ----------------
__global__ __launch_bounds__(256) void norm_rope(const unsigned short* __restrict__ raw,
                                                 int stride,
                                                 unsigned short* __restrict__ outp,
                                                 const float* __restrict__ w,
                                                 const float* __restrict__ cs,
                                                 const float* __restrict__ sn, int NH) {
  const int row = blockIdx.x * 4 + (threadIdx.x >> 6);
  const int lane = threadIdx.x & 63;
  const int t = row / NH, h = row - t * NH;
  const unsigned short* src = raw + (size_t)t * stride + h * HD_;
  float u1 = bf2f(src[lane]);
  float u2 = bf2f(src[lane + 64]);
  float ss = u1 * u1 + u2 * u2;
#pragma unroll
  for (int m = 1; m < 64; m <<= 1) ss += __shfl_xor(ss, m);
  float rr = rsqrtf(ss * (1.f / 128.f) + 1e-6f);
  float c = cs[(size_t)t * HD_ + lane];  // cos[d] == cos[d+64] (concat(freqs,freqs))
  float s = sn[(size_t)t * HD_ + lane];
  float a = u1 * rr * w[lane];
  float b = u2 * rr * w[lane + 64];
  unsigned short* dst = outp + ((size_t)h * T_ + t) * HD_;
  dst[lane]      = f2bf(a * c - b * s);
  dst[lane + 64] = f2bf(b * c + a * s);
}

// ---------------- 256x256 8-phase GEMM (optional split-K via blockIdx.z) ----------------
// C(M,N) = A(M,K)bf16 * Bt(N,K)bf16, row strides LDA. KLEN = K extent per z-slice;
// z-slice kz offsets A/Bt by kz*KLEN and (f32 out) C by kz*M*N partial buffer.
// Schedule identical to R5 (4 phases/K-step, slot-ring staging, counted vmcnt(4)).
template <int MQ, int NQ>
__device__ __forceinline__ void mfma_quad(f32x4 (&acc)[2][4][2][2], bf16x8 (&af)[4][2],
                                          bf16x8 (&BF)[2][2]) {
  __builtin_amdgcn_s_setprio(1);
#pragma unroll
  for (int fm = 0; fm < 4; ++fm)
#pragma unroll
    for (int fn = 0; fn < 2; ++fn) {
      f32x4 a = acc[MQ][fm][NQ][fn];
      a = __builtin_amdgcn_mfma_f32_16x16x32_bf16(af[fm][0], BF[fn][0], a, 0, 0, 0);
      a = __builtin_amdgcn_mfma_f32_16x16x32_bf16(af[fm][1], BF[fn][1], a, 0, 0, 0);
      acc[MQ][fm][NQ][fn] = a;
    }
  __builtin_amdgcn_s_setprio(0);
}

template <int OUTF32>
__global__ __launch_bounds__(512, 2) void gemm256(const unsigned short* __restrict__ A,
                                                  const unsigned short* __restrict__ Bt,
                                                  void* __restrict__ Cv, int M, int N,
                                                  int KLEN, int LDA) {
  __shared__ __align__(16) unsigned short lds[65536];  // A: [2][2][128][64] then B
  const int tid = threadIdx.x;
  const int wid = tid >> 6, lane = tid & 63;
  const int lr = lane & 15, lhi = lane >> 4, lhi8 = lhi * 8;
  const int wr = wid >> 2, wcn = wid & 3;
  const int wr64 = wr * 64, wcn32 = wcn * 32;

  // XCD-aware swizzle over the whole grid (nwg % 8 == 0); derive (bx, by, kz)
  int flat = (blockIdx.z * gridDim.y + blockIdx.y) * gridDim.x + blockIdx.x;
  int nwg = gridDim.x * gridDim.y * gridDim.z;
  int swz = (flat & 7) * (nwg >> 3) + (flat >> 3);
  const int bx = swz & 7;
  const int rest = swz >> 3;
  const int by = rest % gridDim.y;
  const int kz = rest / gridDim.y;
  const int brow = bx * 256;
  const int bcol = by * 256;

  A += (size_t)kz * KLEN;
  Bt += (size_t)kz * KLEN;

  const int nt = KLEN >> 6;

  f32x4 acc[2][4][2][2];
#pragma unroll
  for (int a = 0; a < 2; ++a)
#pragma unroll
    for (int b = 0; b < 4; ++b)
#pragma unroll
      for (int c = 0; c < 2; ++c)
#pragma unroll
        for (int d = 0; d < 2; ++d) acc[a][b][c][d] = (f32x4){0.f, 0.f, 0.f, 0.f};

  const int sl8 = ((lane & 7) ^ (lane >> 3)) * 8;
  const size_t gA0 = (size_t)(brow + wid * 16 + (lane >> 3)) * LDA + sl8;
  const size_t gB0 = (size_t)(bcol + wid * 16 + (lane >> 3)) * LDA + sl8;
  const int ldst0 = wid * 1024;

  auto stageA = [&](int ddB, int half, int ktp) {
#pragma unroll
    for (int l = 0; l < 2; ++l)
      gload_lds16(A + gA0 + (size_t)(half * 128 + l * 8) * LDA + ktp * 64,
                  &lds[ddB + half * 8192 + ldst0 + l * 512]);
  };
  auto stageB = [&](int ddB, int half, int ktp) {
#pragma unroll
    for (int l = 0; l < 2; ++l)
      gload_lds16(Bt + gB0 + (size_t)(half * 128 + l * 8) * LDA + ktp * 64,
                  &lds[32768 + ddB + half * 8192 + ldst0 + l * 512]);
  };

  bf16x8 af[4][2], bf0[2][2], bf1[2][2];
  auto readA = [&](int dB, int mqOff) {
#pragma unroll
    for (int fm = 0; fm < 4; ++fm) {
      int row = wr64 + fm * 16 + lr;
      int sw = (row & 7) << 3;
      int base = dB + mqOff + row * 64;
      af[fm][0] = *(const bf16x8*)&lds[base + (lhi8 ^ sw)];
      af[fm][1] = *(const bf16x8*)&lds[base + ((32 + lhi8) ^ sw)];
    }
  };
  auto readB = [&](int dB, int nqOff, bf16x8 (&bf)[2][2]) {
#pragma unroll
    for (int fn = 0; fn < 2; ++fn) {
      int row = wcn32 + fn * 16 + lr;
      int sw = (row & 7) << 3;
      int base = 32768 + dB + nqOff + row * 64;
      bf[fn][0] = *(const bf16x8*)&lds[base + (lhi8 ^ sw)];
      bf[fn][1] = *(const bf16x8*)&lds[base + ((32 + lhi8) ^ sw)];
    }
  };

  // prologue: full step0 -> dbuf0; step1 A0,B1 -> dbuf1 (invariant: 4 in flight)
  stageA(0, 0, 0); stageA(0, 1, 0); stageB(0, 0, 0); stageB(0, 1, 0);
  stageA(16384, 0, 1); stageB(16384, 1, 1);
  asm volatile("s_waitcnt vmcnt(4)" ::: "memory");
  __builtin_amdgcn_s_barrier();

  for (int t = 0; t < nt; ++t) {
    const int dB = (t & 1) ? 16384 : 0;
    const int dN = 16384 - dB;
    readA(dB, 0);
    readB(dB, 0, bf0);
    if (t + 1 < nt) stageA(dN, 1, t + 1);
    __builtin_amdgcn_s_barrier();
    mfma_quad<0, 0>(acc, af, bf0);
    __builtin_amdgcn_s_barrier();
    readB(dB, 8192, bf1);
    if (t + 1 < nt) stageB(dN, 0, t + 1);
    __builtin_amdgcn_s_barrier();
    mfma_quad<0, 1>(acc, af, bf1);
    __builtin_amdgcn_s_barrier();
    readA(dB, 8192);
    if (t + 2 < nt) stageA(dB, 0, t + 2);
    __builtin_amdgcn_s_barrier();
    mfma_quad<1, 1>(acc, af, bf1);
    __builtin_amdgcn_s_barrier();
    if (t + 2 < nt) stageB(dB, 1, t + 2);
    __builtin_amdgcn_s_barrier();
    mfma_quad<1, 0>(acc, af, bf0);
    if (t < nt - 2) asm volatile("s_waitcnt vmcnt(4)" ::: "memory");
    else if (t == nt - 2) asm volatile("s_waitcnt vmcnt(0)" ::: "memory");
    __builtin_amdgcn_s_barrier();
  }

  float* Cf = (float*)Cv + (size_t)kz * M * N;
#pragma unroll
  for (int mq = 0; mq < 2; ++mq)
#pragma unroll
    for (int fm = 0; fm < 4; ++fm)
#pragma unroll
      for (int nq = 0; nq < 2; ++nq)
#pragma unroll
        for (int fn = 0; fn < 2; ++fn) {
          int col = bcol + nq * 128 + wcn32 + fn * 16 + lr;
#pragma unroll
          for (int r = 0; r < 4; ++r) {
            int row = brow + mq * 128 + wr64 + fm * 16 + lhi * 4 + r;
            if (OUTF32)
              Cf[(size_t)row * N + col] = acc[mq][fm][nq][fn][r];
            else
              ((unsigned short*)Cv)[(size_t)row * N + col] = f2bf(acc[mq][fm][nq][fn][r]);
          }
        }
}

// ---------------- causal flash attention: 2 heads per block ----------------
// 512 thr = 8 waves; waves 0-3 -> head 2p, waves 4-7 -> head 2p+1 (same KV group).
// K/V tiles (64) staged ONCE per block (double-buffered, pre-swizzled source).
// Per-wave math identical to R4 (swapped QK^T, in-register softmax, defer-max).
__global__ __launch_bounds__(512) void flash_attn(const unsigned short* __restrict__ q,
                                                  const unsigned short* __restrict__ k,
                                                  const unsigned short* __restrict__ vt,
                                                  unsigned short* __restrict__ attnb) {
  const int pairIdx = blockIdx.y;
  const int g = pairIdx >> 1;  // GS = 4, 2 heads/block
  const int qc = gridDim.x - 1 - blockIdx.x;  // heavy chunks dispatched first
  const int tid = threadIdx.x;
  const int wid = tid >> 6;
  const int lane = tid & 63;
  const int lr = lane & 15, lhi = lane >> 4;
  const int h = pairIdx * 2 + (wid >> 2);
  const int q0 = qc * 64 + (wid & 3) * 16;

  __shared__ __align__(16) unsigned short Ks[2][64 * HD_];   // 2 x 16 KB
  __shared__ __align__(16) unsigned short Vs[2][HD_ * 64];   // 2 x 16 KB
  __shared__ __align__(16) unsigned short p_lds_all[8][16 * 64];  // 16 KB
  unsigned short* p_lds = p_lds_all[wid];

  const unsigned short* kg = k + (size_t)g * T_ * HD_;
  const unsigned short* vg = vt + (size_t)g * HD_ * T_;

  // staging source offsets (pre-swizzled): 2 x 16B per thread for each of K, V
  int ko[2], vo[2];
#pragma unroll
  for (int p = 0; p < 2; ++p) {
    int ob = (p * 512 + tid) * 16;
    int krow = ob >> 8, kb = ob & 255;
    ko[p] = krow * HD_ + ((kb ^ ((krow & 7) << 4)) >> 1);
    int vrow = ob >> 7, vb2 = ob & 127;
    vo[p] = vrow * T_ + ((vb2 ^ ((vrow & 7) << 4)) >> 1);
  }
  const int lbase = wid * 512;

  const int sx = (lr & 7) << 4;
  const float scale2 = 0.08838834764831845f * 1.4426950408889634f;

  bf16x8 qf[4];
  {
    const unsigned short* qrow = q + ((size_t)h * T_ + q0 + lr) * HD_ + lhi * 8;
#pragma unroll
    for (int c = 0; c < 4; ++c) qf[c] = *(const bf16x8*)(qrow + c * 32);
  }
  f32x4 accO[8];
#pragma unroll
  for (int i = 0; i < 8; ++i) accO[i] = (f32x4){0.f, 0.f, 0.f, 0.f};
  float mrow = -3e38f;
  float lrow = 0.f;

  const int ntile = qc + 1;

#pragma unroll
  for (int p = 0; p < 2; ++p) {
    gload_lds16(kg + ko[p], &Ks[0][p * 4096 + lbase]);
    gload_lds16(vg + vo[p], &Vs[0][p * 4096 + lbase]);
  }
  __syncthreads();

  for (int kt = 0; kt < ntile; ++kt) {
    const int b = kt & 1;
    const int kv0 = kt << 6;
    if (kt + 1 < ntile) {
      const size_t kofs = (size_t)(kv0 + 64) * HD_;
#pragma unroll
      for (int p = 0; p < 2; ++p) {
        gload_lds16(kg + kofs + ko[p], &Ks[b ^ 1][p * 4096 + lbase]);
        gload_lds16(vg + (kv0 + 64) + vo[p], &Vs[b ^ 1][p * 4096 + lbase]);
      }
    }
    f32x4 st[4];
    __builtin_amdgcn_s_setprio(1);
#pragma unroll
    for (int j = 0; j < 4; ++j) {
      st[j] = (f32x4){0.f, 0.f, 0.f, 0.f};
      const int krow = j * 16 + lr;
#pragma unroll
      for (int c = 0; c < 4; ++c) {
        bf16x8 kf = *(const bf16x8*)&Ks[b][krow * HD_ + (((c * 64 + lhi * 16) ^ sx) >> 1)];
        st[j] = __builtin_amdgcn_mfma_f32_16x16x32_bf16(kf, qf[c], st[j], 0, 0, 0);
      }
    }
    __builtin_amdgcn_s_setprio(0);
    if (kt == ntile - 1) {
#pragma unroll
      for (int j = 0; j < 4; ++j)
#pragma unroll
        for (int r = 0; r < 4; ++r)
          st[j][r] = (kv0 + j * 16 + lhi * 4 + r <= q0 + lr) ? st[j][r] * scale2 : -3e38f;
    } else {
#pragma unroll
      for (int j = 0; j < 4; ++j)
#pragma unroll
        for (int r = 0; r < 4; ++r) st[j][r] *= scale2;
    }
    float pm = st[0][0];
#pragma unroll
    for (int j = 0; j < 4; ++j)
#pragma unroll
      for (int r = 0; r < 4; ++r) pm = fmaxf(pm, st[j][r]);
    pm = fmaxf(pm, __shfl_xor(pm, 16));
    pm = fmaxf(pm, __shfl_xor(pm, 32));
    if (!__all(pm - mrow <= 8.f)) {
      float mnew = fmaxf(mrow, pm);
      float al = __builtin_amdgcn_exp2f(mrow - mnew);
      mrow = mnew;
      lrow *= al;
      float a0 = __shfl(al, lhi * 4 + 0);
      float a1 = __shfl(al, lhi * 4 + 1);
      float a2 = __shfl(al, lhi * 4 + 2);
      float a3 = __shfl(al, lhi * 4 + 3);
#pragma unroll
      for (int dt = 0; dt < 8; ++dt) {
        accO[dt][0] *= a0; accO[dt][1] *= a1; accO[dt][2] *= a2; accO[dt][3] *= a3;
      }
    }
    float ps = 0.f;
#pragma unroll
    for (int j = 0; j < 4; ++j)
#pragma unroll
      for (int r = 0; r < 4; ++r) {
        float e = __builtin_amdgcn_exp2f(st[j][r] - mrow);
        st[j][r] = e;
        ps += e;
      }
    ps += __shfl_xor(ps, 16);
    ps += __shfl_xor(ps, 32);
    lrow += ps;
#pragma unroll
    for (int j = 0; j < 4; ++j) {
      u16x4 pw;
      pw[0] = f2bf(st[j][0]); pw[1] = f2bf(st[j][1]);
      pw[2] = f2bf(st[j][2]); pw[3] = f2bf(st[j][3]);
      *(u16x4*)&p_lds[lr * 64 + (((j * 32 + lhi * 8) ^ sx) >> 1)] = pw;
    }
    bf16x8 pa0 = *(const bf16x8*)&p_lds[lr * 64 + (((lhi * 16) ^ sx) >> 1)];
    bf16x8 pa1 = *(const bf16x8*)&p_lds[lr * 64 + (((64 + lhi * 16) ^ sx) >> 1)];
    __builtin_amdgcn_s_setprio(1);
#pragma unroll
    for (int dt = 0; dt < 8; ++dt) {
      const int vrow = dt * 16 + lr;
      bf16x8 vf0 = *(const bf16x8*)&Vs[b][vrow * 64 + (((lhi * 16) ^ sx) >> 1)];
      bf16x8 vf1 = *(const bf16x8*)&Vs[b][vrow * 64 + (((64 + lhi * 16) ^ sx) >> 1)];
      accO[dt] = __builtin_amdgcn_mfma_f32_16x16x32_bf16(pa0, vf0, accO[dt], 0, 0, 0);
      accO[dt] = __builtin_amdgcn_mfma_f32_16x16x32_bf16(pa1, vf1, accO[dt], 0, 0, 0);
    }
    __builtin_amdgcn_s_setprio(0);
    __syncthreads();
  }
  float rinv = 1.f / lrow;
  float i0 = __shfl(rinv, lhi * 4 + 0);
  float i1 = __shfl(rinv, lhi * 4 + 1);
  float i2 = __shfl(rinv, lhi * 4 + 2);
  float i3 = __shfl(rinv, lhi * 4 + 3);
  float iv[4] = {i0, i1, i2, i3};
#pragma unroll
  for (int r = 0; r < 4; ++r) {
    size_t rowoff = (size_t)(q0 + lhi * 4 + r) * (H_ * HD_) + h * HD_;
#pragma unroll
    for (int dt = 0; dt < 8; ++dt) attnb[rowoff + dt * 16 + lr] = f2bf(accO[dt][r] * iv[r]);
  }
}

extern "C" void kernel_launch(void* const* d_in, const int* in_sizes, int n_in,
                              void* d_out, int out_size, void* d_ws, size_t ws_size,
                              hipStream_t stream) {
  const float* x = (const float*)d_in[0];
  // d_in[1] = mask (bool) — causal mask computed analytically, unused
  const float* cosT = (const float*)d_in[2];
  const float* sinT = (const float*)d_in[3];
  const float* Wq = (const float*)d_in[4];
  const float* Wk = (const float*)d_in[5];
  const float* Wv = (const float*)d_in[6];
  const float* Wo = (const float*)d_in[7];
  const float* qn = (const float*)d_in[8];
  const float* kn = (const float*)d_in[9];

  unsigned char* w = (unsigned char*)d_ws;
  unsigned short* xb     = (unsigned short*)(w);             // 16 MB (T,D) bf16
  unsigned short* WqkvT  = (unsigned short*)(w + 16777216);  // 48 MB (6144,4096) bf16
  unsigned short* qkvraw = (unsigned short*)(w + 67108864);  // 24 MB (T,6144) bf16
  unsigned short* qbuf   = (unsigned short*)(w + 92274688);  // 16 MB (H,T,HD)
  unsigned short* kbuf   = (unsigned short*)(w + 109051904); // 4 MB (G,T,HD)
  unsigned short* vtb    = (unsigned short*)(w + 113246208); // 4 MB (G,HD,T) -> 117.4 MB
  unsigned short* WoT    = WqkvT;  // alias: Wqkv dead after QKV GEMM (32 MB of 48)
  unsigned short* attnb  = xb;     // alias: x dead after QKV GEMM
  float* p0 = (float*)(w + 50331648);  // 64 MB split-K partials; overlays WqkvT tail +
                                       // qkvraw + qbuf + kbuf + vtb (all dead post-flash)

  convert_bf16<<<dim3(4096), dim3(256), 0, stream>>>(x, xb);
  transpose_convert<<<dim3(64, 64), dim3(256), 0, stream>>>(Wq, WqkvT, 4096, 4096);
  transpose_convert<<<dim3(64, 16), dim3(256), 0, stream>>>(Wk, WqkvT + (size_t)4096 * 4096, 4096, 1024);
  transpose_convert<<<dim3(64, 16), dim3(256), 0, stream>>>(Wv, WqkvT + (size_t)5120 * 4096, 4096, 1024);

  // fused QKV projection: (2048,4096) x (6144,4096)^T -> (2048,6144) bf16
  gemm256<0><<<dim3(8, 24, 1), dim3(512), 0, stream>>>(xb, WqkvT, (void*)qkvraw, 2048, 6144, 4096, 4096);

  norm_rope<<<dim3(16384), dim3(256), 0, stream>>>(qkvraw, 6144, qbuf, qn, cosT, sinT, H_);
  norm_rope<<<dim3(4096), dim3(256), 0, stream>>>(qkvraw + 4096, 6144, kbuf, kn, cosT, sinT, G_);
  transpose_v<<<dim3(32, 2, 8), dim3(256), 0, stream>>>(qkvraw + 5120, vtb, 6144);
  transpose_convert<<<dim3(64, 64), dim3(256), 0, stream>>>(Wo, WoT, 4096, 4096);

  flash_attn<<<dim3(32, 16), dim3(512), 0, stream>>>(qbuf, kbuf, vtb, attnb);

  // Wo projection, split-K x2 in ONE dispatch (256 blocks = full GPU), then add
  gemm256<1><<<dim3(8, 16, 2), dim3(512), 0, stream>>>(attnb, WoT, (void*)p0, 2048, 4096, 2048, 4096);
  add_halves<<<dim3(2048), dim3(256), 0, stream>>>(p0, (float*)d_out);
}

// Round 7
// 350.164 us; speedup vs baseline: 2.5954x; 1.0586x over previous
//
#include <hip/hip_runtime.h>

#define T_ 2048
#define D_ 4096
#define H_ 32
#define G_ 8
#define HD_ 128

typedef float f32x4 __attribute__((ext_vector_type(4)));
typedef __bf16 bf16x8 __attribute__((ext_vector_type(8)));
typedef unsigned short u16x8 __attribute__((ext_vector_type(8)));
typedef unsigned short u16x4 __attribute__((ext_vector_type(4)));

__device__ __forceinline__ unsigned short f2bf(float f) {
  unsigned u = __builtin_bit_cast(unsigned, f);
  u += 0x7FFFu + ((u >> 16) & 1u);
  return (unsigned short)(u >> 16);
}
__device__ __forceinline__ float bf2f(unsigned short h) {
  return __builtin_bit_cast(float, (unsigned)h << 16);
}

__device__ __forceinline__ void gload_lds16(const unsigned short* g, unsigned short* l) {
  __builtin_amdgcn_global_load_lds((const __attribute__((address_space(1))) void*)g,
                                   (__attribute__((address_space(3))) void*)l, 16, 0, 0);
}

// ---------------- elementwise f32 -> bf16 ----------------
__global__ __launch_bounds__(256) void convert_bf16(const float* __restrict__ in,
                                                    unsigned short* __restrict__ out) {
  const size_t i = ((size_t)blockIdx.x * 256 + threadIdx.x) * 8;
  float4 a = *(const float4*)(in + i);
  float4 b = *(const float4*)(in + i + 4);
  u16x8 o;
  o[0] = f2bf(a.x); o[1] = f2bf(a.y); o[2] = f2bf(a.z); o[3] = f2bf(a.w);
  o[4] = f2bf(b.x); o[5] = f2bf(b.y); o[6] = f2bf(b.z); o[7] = f2bf(b.w);
  *(u16x8*)(out + i) = o;
}

// ---------------- tiled transpose + convert: W (R,C) f32 -> Wt (C,R) bf16 ----------------
__global__ __launch_bounds__(256) void transpose_convert(const float* __restrict__ Wm,
                                                         unsigned short* __restrict__ Wt,
                                                         int R, int C) {
  __shared__ float tile[64][65];
  const int r0 = blockIdx.x * 64, c0 = blockIdx.y * 64;
  const int lr4 = threadIdx.x >> 6, lc = threadIdx.x & 63;
#pragma unroll
  for (int i = 0; i < 16; ++i) {
    int r = i * 4 + lr4;
    tile[r][lc] = Wm[(size_t)(r0 + r) * C + c0 + lc];
  }
  __syncthreads();
#pragma unroll
  for (int i = 0; i < 16; ++i) {
    int r = i * 4 + lr4;
    Wt[(size_t)(c0 + r) * R + r0 + lc] = f2bf(tile[lc][r]);
  }
}

// ---------------- transpose v: (T, stride) bf16 cols -> (G, HD, T) bf16 ----------------
__global__ __launch_bounds__(256) void transpose_v(const unsigned short* __restrict__ v,
                                                   unsigned short* __restrict__ vt, int stride) {
  __shared__ unsigned short tile[64][65];
  const int t0 = blockIdx.x * 64, d0 = blockIdx.y * 64, g = blockIdx.z;
  const int lr4 = threadIdx.x >> 6, lc = threadIdx.x & 63;
#pragma unroll
  for (int i = 0; i < 16; ++i) {
    int r = i * 4 + lr4;
    tile[r][lc] = v[(size_t)(t0 + r) * stride + g * HD_ + d0 + lc];
  }
  __syncthreads();
#pragma unroll
  for (int i = 0; i < 16; ++i) {
    int r = i * 4 + lr4;
    vt[((size_t)g * HD_ + d0 + r) * T_ + t0 + lc] = tile[lc][r];
  }
}

// ---------------- RMSNorm + RoPE; (T, stride) bf16 -> (NH, T, HD) bf16 ----------------
__global__ __launch_bounds__(256) void norm_rope(const unsigned short* __restrict__ raw,
                                                 int stride,
                                                 unsigned short* __restrict__ outp,
                                                 const float* __restrict__ w,
                                                 const float* __restrict__ cs,
                                                 const float* __restrict__ sn, int NH) {
  const int row = blockIdx.x * 4 + (threadIdx.x >> 6);
  const int lane = threadIdx.x & 63;
  const int t = row / NH, h = row - t * NH;
  const unsigned short* src = raw + (size_t)t * stride + h * HD_;
  float u1 = bf2f(src[lane]);
  float u2 = bf2f(src[lane + 64]);
  float ss = u1 * u1 + u2 * u2;
#pragma unroll
  for (int m = 1; m < 64; m <<= 1) ss += __shfl_xor(ss, m);
  float rr = rsqrtf(ss * (1.f / 128.f) + 1e-6f);
  float c = cs[(size_t)t * HD_ + lane];  // cos[d] == cos[d+64] (concat(freqs,freqs))
  float s = sn[(size_t)t * HD_ + lane];
  float a = u1 * rr * w[lane];
  float b = u2 * rr * w[lane + 64];
  unsigned short* dst = outp + ((size_t)h * T_ + t) * HD_;
  dst[lane]      = f2bf(a * c - b * s);
  dst[lane + 64] = f2bf(b * c + a * s);
}

// ---------------- 256 x (64*NF) phased GEMM: C(M,N) = A(M,K)bf16 * Bt(N,K)bf16 ----------------
// 512 thr = 8 waves (2 Mw x 4 Nw); wave tile 128x(16*NF) split as mq in {0,1} x fm x fn.
// BK=64. LDS = 2dbuf x (A 256x64 + B BN x 64) bf16: NF=2 -> 96 KB, NF=3 -> 112 KB.
// Stage units: A0..A3, B0..B(NF-1), each 64 rows = 1 gload_lds16/thread.
// Slot-ring prefetch depth ~1.5; counted vmcnt(2) per step (never 0 mid-loop).
// Swizzle (rule #21 involution): linear LDS dest, global src col-slot ^= row&7,
// read addr slot ^= row&7 (2-way bank aliasing = free).
template <int NF, int MQ, int F0, int F1>
__device__ __forceinline__ void mfma_g(f32x4 (&acc)[2][4][NF], bf16x8 (&af)[4][2],
                                       bf16x8 (&bf)[NF][2]) {
  __builtin_amdgcn_s_setprio(1);
#pragma unroll
  for (int fm = 0; fm < 4; ++fm)
#pragma unroll
    for (int fn = F0; fn < F1; ++fn) {
      f32x4 a = acc[MQ][fm][fn];
      a = __builtin_amdgcn_mfma_f32_16x16x32_bf16(af[fm][0], bf[fn][0], a, 0, 0, 0);
      a = __builtin_amdgcn_mfma_f32_16x16x32_bf16(af[fm][1], bf[fn][1], a, 0, 0, 0);
      acc[MQ][fm][fn] = a;
    }
  __builtin_amdgcn_s_setprio(0);
}

template <int NF, int OUTF32>
__global__ __launch_bounds__(512, 2) void gemm2(const unsigned short* __restrict__ A,
                                                const unsigned short* __restrict__ Bt,
                                                void* __restrict__ Cv, int M, int N,
                                                int K, int LDA) {
  constexpr int BN = NF * 64;
  constexpr int BBUF = NF * 4096;  // ushorts per dbuf for B
  __shared__ __align__(16) unsigned short lds[32768 + 2 * BBUF];
  const int tid = threadIdx.x;
  const int wid = tid >> 6, lane = tid & 63;
  const int lr = lane & 15, lhi = lane >> 4;
  const int wr = wid >> 2, wcn = wid & 3;
  const int wr64 = wr * 64;

  // XCD-aware swizzle (nwg % 8 == 0; M/256 == 8)
  int flat = blockIdx.y * gridDim.x + blockIdx.x;
  int nwg = gridDim.x * gridDim.y;
  int swz = (flat & 7) * (nwg >> 3) + (flat >> 3);
  const int brow = (swz & 7) * 256;
  const int bcol = (swz >> 3) * BN;

  const int nt = K >> 6;

  f32x4 acc[2][4][NF];
#pragma unroll
  for (int a = 0; a < 2; ++a)
#pragma unroll
    for (int b = 0; b < 4; ++b)
#pragma unroll
      for (int c = 0; c < NF; ++c) acc[a][b][c] = (f32x4){0.f, 0.f, 0.f, 0.f};

  // staging: unit = 64 rows x 64 cols bf16 (8 KB) = 512 thr x 16 B
  const int t8 = tid >> 3;                          // row within unit
  const int srcCol = ((tid & 7) ^ (t8 & 7)) * 8;    // inverse-swizzled source col
  auto stageA = [&](int d, int u, int ktp) {
    gload_lds16(A + (size_t)(brow + u * 64 + t8) * LDA + ktp * 64 + srcCol,
                &lds[d * 16384 + u * 4096 + tid * 8]);
  };
  auto stageB = [&](int d, int v, int ktp) {
    gload_lds16(Bt + (size_t)(bcol + v * 64 + t8) * LDA + ktp * 64 + srcCol,
                &lds[32768 + d * BBUF + v * 4096 + tid * 8]);
  };

  bf16x8 af[4][2], bf[NF][2];
  auto readA = [&](int d, int mq) {
#pragma unroll
    for (int fm = 0; fm < 4; ++fm) {
      int row = mq * 128 + wr64 + fm * 16 + lr;
      int base = d * 16384 + row * 64;
      int sw = (row & 7) << 3;
      af[fm][0] = *(const bf16x8*)&lds[base + ((lhi * 8) ^ sw)];
      af[fm][1] = *(const bf16x8*)&lds[base + ((32 + lhi * 8) ^ sw)];
    }
  };
  auto readBf = [&](int d, int fn, bf16x8 (&slot)[2]) {
    int row = wcn * (16 * NF) + fn * 16 + lr;
    int base = 32768 + d * BBUF + row * 64;
    int sw = (row & 7) << 3;
    slot[0] = *(const bf16x8*)&lds[base + ((lhi * 8) ^ sw)];
    slot[1] = *(const bf16x8*)&lds[base + ((32 + lhi * 8) ^ sw)];
  };

  // prologue: step0 full -> d0; A-mq0(step1) -> d1  (nt >= 2 always here)
  stageA(0, 0, 0); stageA(0, 1, 0); stageA(0, 2, 0); stageA(0, 3, 0);
#pragma unroll
  for (int v = 0; v < NF; ++v) stageB(0, v, 0);
  stageA(1, 0, 1); stageA(1, 1, 1);
  asm volatile("s_waitcnt vmcnt(2)" ::: "memory");
  __builtin_amdgcn_s_barrier();

  for (int t = 0; t < nt; ++t) {
    const int d = t & 1, dn = d ^ 1;
    if constexpr (NF == 2) {
      // P0: mq0 full width
      readA(d, 0); readBf(d, 0, bf[0]); readBf(d, 1, bf[1]);
      if (t + 1 < nt) { stageA(dn, 2, t + 1); stageA(dn, 3, t + 1);
                        stageB(dn, 0, t + 1); stageB(dn, 1, t + 1); }
      __builtin_amdgcn_s_barrier();
      mfma_g<NF, 0, 0, 2>(acc, af, bf);
      __builtin_amdgcn_s_barrier();
      // P1: mq1 full width
      readA(d, 1);
      if (t + 2 < nt) { stageA(d, 0, t + 2); stageA(d, 1, t + 2); }
      __builtin_amdgcn_s_barrier();
      mfma_g<NF, 1, 0, 2>(acc, af, bf);
      if (t < nt - 2) asm volatile("s_waitcnt vmcnt(2)" ::: "memory");
      else if (t == nt - 2) asm volatile("s_waitcnt vmcnt(0)" ::: "memory");
      __builtin_amdgcn_s_barrier();
    } else {
      // P0: mq0 x fn{0,1}
      readA(d, 0); readBf(d, 0, bf[0]); readBf(d, 1, bf[1]);
      if (t + 1 < nt) { stageA(dn, 2, t + 1); stageA(dn, 3, t + 1); }
      __builtin_amdgcn_s_barrier();
      mfma_g<NF, 0, 0, 2>(acc, af, bf);
      __builtin_amdgcn_s_barrier();
      // P1: mq0 x fn{2}
      readBf(d, 2, bf[2]);
      if (t + 1 < nt) { stageB(dn, 0, t + 1); stageB(dn, 1, t + 1); stageB(dn, 2, t + 1); }
      __builtin_amdgcn_s_barrier();
      mfma_g<NF, 0, 2, 3>(acc, af, bf);
      __builtin_amdgcn_s_barrier();
      // P2: mq1 x fn{0,1}
      readA(d, 1);
      if (t + 2 < nt) { stageA(d, 0, t + 2); stageA(d, 1, t + 2); }
      __builtin_amdgcn_s_barrier();
      mfma_g<NF, 1, 0, 2>(acc, af, bf);
      __builtin_amdgcn_s_barrier();
      // P3: mq1 x fn{2}
      mfma_g<NF, 1, 2, 3>(acc, af, bf);
      if (t < nt - 2) asm volatile("s_waitcnt vmcnt(2)" ::: "memory");
      else if (t == nt - 2) asm volatile("s_waitcnt vmcnt(0)" ::: "memory");
      __builtin_amdgcn_s_barrier();
    }
  }

  // epilogue
#pragma unroll
  for (int mq = 0; mq < 2; ++mq)
#pragma unroll
    for (int fm = 0; fm < 4; ++fm)
#pragma unroll
      for (int fn = 0; fn < NF; ++fn) {
        int col = bcol + wcn * (16 * NF) + fn * 16 + lr;
#pragma unroll
        for (int r = 0; r < 4; ++r) {
          int row = brow + mq * 128 + wr64 + fm * 16 + lhi * 4 + r;
          if (OUTF32)
            ((float*)Cv)[(size_t)row * N + col] = acc[mq][fm][fn][r];
          else
            ((unsigned short*)Cv)[(size_t)row * N + col] = f2bf(acc[mq][fm][fn][r]);
        }
      }
}

// ---------------- causal flash attention: 2 heads per block (unchanged from R6) ----------------
__global__ __launch_bounds__(512) void flash_attn(const unsigned short* __restrict__ q,
                                                  const unsigned short* __restrict__ k,
                                                  const unsigned short* __restrict__ vt,
                                                  unsigned short* __restrict__ attnb) {
  const int pairIdx = blockIdx.y;
  const int g = pairIdx >> 1;  // GS = 4, 2 heads/block
  const int qc = gridDim.x - 1 - blockIdx.x;  // heavy chunks dispatched first
  const int tid = threadIdx.x;
  const int wid = tid >> 6;
  const int lane = tid & 63;
  const int lr = lane & 15, lhi = lane >> 4;
  const int h = pairIdx * 2 + (wid >> 2);
  const int q0 = qc * 64 + (wid & 3) * 16;

  __shared__ __align__(16) unsigned short Ks[2][64 * HD_];
  __shared__ __align__(16) unsigned short Vs[2][HD_ * 64];
  __shared__ __align__(16) unsigned short p_lds_all[8][16 * 64];
  unsigned short* p_lds = p_lds_all[wid];

  const unsigned short* kg = k + (size_t)g * T_ * HD_;
  const unsigned short* vg = vt + (size_t)g * HD_ * T_;

  int ko[2], vo[2];
#pragma unroll
  for (int p = 0; p < 2; ++p) {
    int ob = (p * 512 + tid) * 16;
    int krow = ob >> 8, kb = ob & 255;
    ko[p] = krow * HD_ + ((kb ^ ((krow & 7) << 4)) >> 1);
    int vrow = ob >> 7, vb2 = ob & 127;
    vo[p] = vrow * T_ + ((vb2 ^ ((vrow & 7) << 4)) >> 1);
  }
  const int lbase = wid * 512;

  const int sx = (lr & 7) << 4;
  const float scale2 = 0.08838834764831845f * 1.4426950408889634f;

  bf16x8 qf[4];
  {
    const unsigned short* qrow = q + ((size_t)h * T_ + q0 + lr) * HD_ + lhi * 8;
#pragma unroll
    for (int c = 0; c < 4; ++c) qf[c] = *(const bf16x8*)(qrow + c * 32);
  }
  f32x4 accO[8];
#pragma unroll
  for (int i = 0; i < 8; ++i) accO[i] = (f32x4){0.f, 0.f, 0.f, 0.f};
  float mrow = -3e38f;
  float lrow = 0.f;

  const int ntile = qc + 1;

#pragma unroll
  for (int p = 0; p < 2; ++p) {
    gload_lds16(kg + ko[p], &Ks[0][p * 4096 + lbase]);
    gload_lds16(vg + vo[p], &Vs[0][p * 4096 + lbase]);
  }
  __syncthreads();

  for (int kt = 0; kt < ntile; ++kt) {
    const int b = kt & 1;
    const int kv0 = kt << 6;
    if (kt + 1 < ntile) {
      const size_t kofs = (size_t)(kv0 + 64) * HD_;
#pragma unroll
      for (int p = 0; p < 2; ++p) {
        gload_lds16(kg + kofs + ko[p], &Ks[b ^ 1][p * 4096 + lbase]);
        gload_lds16(vg + (kv0 + 64) + vo[p], &Vs[b ^ 1][p * 4096 + lbase]);
      }
    }
    f32x4 st[4];
    __builtin_amdgcn_s_setprio(1);
#pragma unroll
    for (int j = 0; j < 4; ++j) {
      st[j] = (f32x4){0.f, 0.f, 0.f, 0.f};
      const int krow = j * 16 + lr;
#pragma unroll
      for (int c = 0; c < 4; ++c) {
        bf16x8 kf = *(const bf16x8*)&Ks[b][krow * HD_ + (((c * 64 + lhi * 16) ^ sx) >> 1)];
        st[j] = __builtin_amdgcn_mfma_f32_16x16x32_bf16(kf, qf[c], st[j], 0, 0, 0);
      }
    }
    __builtin_amdgcn_s_setprio(0);
    if (kt == ntile - 1) {
#pragma unroll
      for (int j = 0; j < 4; ++j)
#pragma unroll
        for (int r = 0; r < 4; ++r)
          st[j][r] = (kv0 + j * 16 + lhi * 4 + r <= q0 + lr) ? st[j][r] * scale2 : -3e38f;
    } else {
#pragma unroll
      for (int j = 0; j < 4; ++j)
#pragma unroll
        for (int r = 0; r < 4; ++r) st[j][r] *= scale2;
    }
    float pm = st[0][0];
#pragma unroll
    for (int j = 0; j < 4; ++j)
#pragma unroll
      for (int r = 0; r < 4; ++r) pm = fmaxf(pm, st[j][r]);
    pm = fmaxf(pm, __shfl_xor(pm, 16));
    pm = fmaxf(pm, __shfl_xor(pm, 32));
    if (!__all(pm - mrow <= 8.f)) {
      float mnew = fmaxf(mrow, pm);
      float al = __builtin_amdgcn_exp2f(mrow - mnew);
      mrow = mnew;
      lrow *= al;
      float a0 = __shfl(al, lhi * 4 + 0);
      float a1 = __shfl(al, lhi * 4 + 1);
      float a2 = __shfl(al, lhi * 4 + 2);
      float a3 = __shfl(al, lhi * 4 + 3);
#pragma unroll
      for (int dt = 0; dt < 8; ++dt) {
        accO[dt][0] *= a0; accO[dt][1] *= a1; accO[dt][2] *= a2; accO[dt][3] *= a3;
      }
    }
    float ps = 0.f;
#pragma unroll
    for (int j = 0; j < 4; ++j)
#pragma unroll
      for (int r = 0; r < 4; ++r) {
        float e = __builtin_amdgcn_exp2f(st[j][r] - mrow);
        st[j][r] = e;
        ps += e;
      }
    ps += __shfl_xor(ps, 16);
    ps += __shfl_xor(ps, 32);
    lrow += ps;
#pragma unroll
    for (int j = 0; j < 4; ++j) {
      u16x4 pw;
      pw[0] = f2bf(st[j][0]); pw[1] = f2bf(st[j][1]);
      pw[2] = f2bf(st[j][2]); pw[3] = f2bf(st[j][3]);
      *(u16x4*)&p_lds[lr * 64 + (((j * 32 + lhi * 8) ^ sx) >> 1)] = pw;
    }
    bf16x8 pa0 = *(const bf16x8*)&p_lds[lr * 64 + (((lhi * 16) ^ sx) >> 1)];
    bf16x8 pa1 = *(const bf16x8*)&p_lds[lr * 64 + (((64 + lhi * 16) ^ sx) >> 1)];
    __builtin_amdgcn_s_setprio(1);
#pragma unroll
    for (int dt = 0; dt < 8; ++dt) {
      const int vrow = dt * 16 + lr;
      bf16x8 vf0 = *(const bf16x8*)&Vs[b][vrow * 64 + (((lhi * 16) ^ sx) >> 1)];
      bf16x8 vf1 = *(const bf16x8*)&Vs[b][vrow * 64 + (((64 + lhi * 16) ^ sx) >> 1)];
      accO[dt] = __builtin_amdgcn_mfma_f32_16x16x32_bf16(pa0, vf0, accO[dt], 0, 0, 0);
      accO[dt] = __builtin_amdgcn_mfma_f32_16x16x32_bf16(pa1, vf1, accO[dt], 0, 0, 0);
    }
    __builtin_amdgcn_s_setprio(0);
    __syncthreads();
  }
  float rinv = 1.f / lrow;
  float i0 = __shfl(rinv, lhi * 4 + 0);
  float i1 = __shfl(rinv, lhi * 4 + 1);
  float i2 = __shfl(rinv, lhi * 4 + 2);
  float i3 = __shfl(rinv, lhi * 4 + 3);
  float iv[4] = {i0, i1, i2, i3};
#pragma unroll
  for (int r = 0; r < 4; ++r) {
    size_t rowoff = (size_t)(q0 + lhi * 4 + r) * (H_ * HD_) + h * HD_;
#pragma unroll
    for (int dt = 0; dt < 8; ++dt) attnb[rowoff + dt * 16 + lr] = f2bf(accO[dt][r] * iv[r]);
  }
}

extern "C" void kernel_launch(void* const* d_in, const int* in_sizes, int n_in,
                              void* d_out, int out_size, void* d_ws, size_t ws_size,
                              hipStream_t stream) {
  const float* x = (const float*)d_in[0];
  // d_in[1] = mask (bool) — causal mask computed analytically, unused
  const float* cosT = (const float*)d_in[2];
  const float* sinT = (const float*)d_in[3];
  const float* Wq = (const float*)d_in[4];
  const float* Wk = (const float*)d_in[5];
  const float* Wv = (const float*)d_in[6];
  const float* Wo = (const float*)d_in[7];
  const float* qn = (const float*)d_in[8];
  const float* kn = (const float*)d_in[9];

  unsigned char* w = (unsigned char*)d_ws;
  unsigned short* xb     = (unsigned short*)(w);             // 16 MB (T,D) bf16
  unsigned short* WqkvT  = (unsigned short*)(w + 16777216);  // 48 MB (6144,4096) bf16
  unsigned short* qkvraw = (unsigned short*)(w + 67108864);  // 24 MB (T,6144) bf16
  unsigned short* qbuf   = (unsigned short*)(w + 92274688);  // 16 MB (H,T,HD)
  unsigned short* kbuf   = (unsigned short*)(w + 109051904); // 4 MB (G,T,HD)
  unsigned short* vtb    = (unsigned short*)(w + 113246208); // 4 MB (G,HD,T) -> 117.4 MB
  unsigned short* WoT    = WqkvT;  // alias: Wqkv dead after QKV GEMM (32 MB of 48)
  unsigned short* attnb  = xb;     // alias: x dead after QKV GEMM

  convert_bf16<<<dim3(4096), dim3(256), 0, stream>>>(x, xb);
  transpose_convert<<<dim3(64, 64), dim3(256), 0, stream>>>(Wq, WqkvT, 4096, 4096);
  transpose_convert<<<dim3(64, 16), dim3(256), 0, stream>>>(Wk, WqkvT + (size_t)4096 * 4096, 4096, 1024);
  transpose_convert<<<dim3(64, 16), dim3(256), 0, stream>>>(Wv, WqkvT + (size_t)5120 * 4096, 4096, 1024);

  // fused QKV projection: (2048,4096) x (6144,4096)^T -> (2048,6144) bf16
  // BN=192 -> grid (8,32) = 256 blocks = full GPU
  gemm2<3, 0><<<dim3(8, 32), dim3(512), 0, stream>>>(xb, WqkvT, (void*)qkvraw, 2048, 6144, 4096, 4096);

  norm_rope<<<dim3(16384), dim3(256), 0, stream>>>(qkvraw, 6144, qbuf, qn, cosT, sinT, H_);
  norm_rope<<<dim3(4096), dim3(256), 0, stream>>>(qkvraw + 4096, 6144, kbuf, kn, cosT, sinT, G_);
  transpose_v<<<dim3(32, 2, 8), dim3(256), 0, stream>>>(qkvraw + 5120, vtb, 6144);
  transpose_convert<<<dim3(64, 64), dim3(256), 0, stream>>>(Wo, WoT, 4096, 4096);

  flash_attn<<<dim3(32, 16), dim3(512), 0, stream>>>(qbuf, kbuf, vtb, attnb);

  // Wo projection: BN=128 -> grid (8,32) = 256 blocks, direct f32 out (no split-K, no add)
  gemm2<2, 1><<<dim3(8, 32), dim3(512), 0, stream>>>(attnb, WoT, d_out, 2048, 4096, 4096, 4096);
}